// Round 20
// baseline (482.860 us; speedup 1.0000x reference)
//
#include <hip/hip_runtime.h>
#include <cstdint>

typedef unsigned short u16;
typedef short bf16x8 __attribute__((ext_vector_type(8)));
typedef float f32x4 __attribute__((ext_vector_type(4)));
typedef u16 u16x8 __attribute__((ext_vector_type(8)));
typedef u16 u16x4 __attribute__((ext_vector_type(4)));

// fast sigmoid: v_exp + v_rcp.
static __device__ __forceinline__ float sigm_fast(float x) {
    return __builtin_amdgcn_rcpf(1.0f + __expf(-x));
}
static __device__ __forceinline__ float b2f(u16 u) {
    union { unsigned i; float f; } v; v.i = ((unsigned)u) << 16; return v.f;
}
static __device__ __forceinline__ u16 f2b(float f) {
    unsigned x = __float_as_uint(f);
    x = x + 0x7fffu + ((x >> 16) & 1u);
    return (u16)(x >> 16);
}
static __device__ __forceinline__ void gload16(const u16* g, u16* l) {
    __builtin_amdgcn_global_load_lds((__attribute__((address_space(1))) void*)(void*)g,
                                     (__attribute__((address_space(3))) void*)l, 16, 0, 0);
}

// ---------------------------------------------------------------------------
// bf16 MFMA GEMM — ROUND-20: waves/SIMD lever to its endpoint. Same proven
// schedule (128x128 tile, BK=64, 64 KiB LDS double-buffer, literal-buffer
// unrolled x2 K-loop, pre-swizzled global_load_lds, T1 XCD swizzle) but
// 1024 THREADS (16 waves, 4Mx4N, 32x32/wave). 2 blocks/CU -> 32 waves/CU
// = 8 waves/SIMD (HW max; round-17's 2->4 gave +21% GEMM).
// __launch_bounds__(1024, 8) caps VGPR at 64 so both blocks stay resident.
// acc[2][2] (16 VGPR) + frags ~16 -> fits. Staging: 1 gload16 each for A/B.
// Epilogue: fp32 [32][132] LDS bounce, 4 phases of 32 rows, f32x4 read +
// u16x4 store per thread (coalesced).
// C = [swish](alpha * A @ Bt^T [+bias(col)] [+res]) -> bf16.
// ---------------------------------------------------------------------------
__global__ __launch_bounds__(1024, 8) void gemm_bf16(
    const u16* A, const u16* Bt, u16* outB,
    const float* resF, const u16* resB, const float* bias, float2* partials,
    int N, int K, int lda, float alpha, int do_swish,
    long long sA, long long sB, long long sC)
{
    __shared__ u16 lds[32768];  // 64 KB
    const int tid = threadIdx.x;
    const int lane = tid & 63;
    const int wid = tid >> 6;            // 0..15
    const int wm = wid >> 2;             // 0..3 -> rows wm*32..+32
    const int wn = wid & 3;              // 0..3 -> cols wn*32..+32

    // ---- T1: bijective XCD swizzle (requires nwg % 8 == 0, else identity) ----
    const int gx = gridDim.x, gy = gridDim.y;
    int flat = blockIdx.y * gx + blockIdx.x;
    const int nwg = gx * gy;
    if ((nwg & 7) == 0 && nwg >= 16) {
        const int q = nwg >> 3;
        flat = (flat & 7) * q + (flat >> 3);
    }
    const int bx = flat % gx;
    const int by = flat / gx;
    const int m0 = by * 128;
    const int n0 = bx * 128;
    const int bz = blockIdx.z;
    const long long cbase = (long long)bz * sC;

    const int srow = tid >> 3;   // 0..127
    const int sslot = tid & 7;   // 0..7

    f32x4 acc[2][2];
#pragma unroll
    for (int i = 0; i < 2; ++i)
#pragma unroll
        for (int j = 0; j < 2; ++j)
#pragma unroll
            for (int r = 0; r < 4; ++r) acc[i][j][r] = 0.0f;

    const u16* Abase = A + (long long)bz * sA + (long long)m0 * lda;
    const u16* Bbase = Bt + (long long)bz * sB + (long long)n0 * K;
    const int NT = K >> 6;   // even at all call sites (K in {256,512,1024})

    auto stage = [&](int buf, int kt) {   // buf literal at every call site
        const u16* Ab = Abase + kt * 64;
        const u16* Bb = Bbase + kt * 64;
        u16* LA = lds + buf * 16384;
        u16* LB = LA + 8192;
        const int gs = (sslot ^ (srow & 7)) * 8;
        gload16(Ab + (long long)srow * lda + gs, LA + srow * 64 + sslot * 8);
        gload16(Bb + (long long)srow * K + gs, LB + srow * 64 + sslot * 8);
    };

    auto compute = [&](int buf) {         // buf literal at every call site
        const u16* LA = lds + buf * 16384;
        const u16* LB = LA + 8192;
#pragma unroll
        for (int ks = 0; ks < 2; ++ks) {
            bf16x8 av[2], bv[2];
            const int sl = ks * 4 + (lane >> 4);
#pragma unroll
            for (int i = 0; i < 2; ++i) {
                const int ar = wm * 32 + i * 16 + (lane & 15);
                av[i] = *(const bf16x8*)(LA + ar * 64 + (sl ^ (ar & 7)) * 8);
            }
#pragma unroll
            for (int j = 0; j < 2; ++j) {
                const int br = wn * 32 + j * 16 + (lane & 15);
                bv[j] = *(const bf16x8*)(LB + br * 64 + (sl ^ (br & 7)) * 8);
            }
#pragma unroll
            for (int i = 0; i < 2; ++i)
#pragma unroll
                for (int j = 0; j < 2; ++j)
                    acc[i][j] = __builtin_amdgcn_mfma_f32_16x16x32_bf16(av[i], bv[j], acc[i][j], 0, 0, 0);
        }
    };

    // ---- K-loop, unrolled x2: buffer indices are compile-time constants ----
    stage(0, 0);
    __syncthreads();
    for (int kt = 0; kt < NT; kt += 2) {
        if (kt + 1 < NT) stage(1, kt + 1);
        compute(0);
        __syncthreads();
        if (kt + 2 < NT) stage(0, kt + 2);
        compute(1);          // NT even -> buf1 always staged by this point
        __syncthreads();
    }
    // loop ends with __syncthreads -> LDS free for epilogue reuse

    // ---- epilogue: fp32 [32][132] LDS bounce, 4 phases of 32 rows ----
    float* ldsC = (float*)lds;           // 32*132*4 = 16.9 KB
    float sacc = 0.0f, ssacc = 0.0f;
    const int lr = tid >> 5;             // 0..31 local row
    const int cg = (tid & 31) * 4;       // 4 cols/thread

#pragma unroll
    for (int p = 0; p < 4; ++p) {
        if (wm == p) {                    // 4 waves (wn=0..3) write their 32x32 slice
#pragma unroll
            for (int i = 0; i < 2; ++i)
#pragma unroll
                for (int j = 0; j < 2; ++j)
#pragma unroll
                    for (int r = 0; r < 4; ++r) {
                        const int rlo = i * 16 + ((lane >> 4) << 2) + r;     // 0..31
                        const int clo = wn * 32 + j * 16 + (lane & 15);      // 0..127
                        ldsC[rlo * 132 + clo] = alpha * acc[i][j][r];
                    }
        }
        __syncthreads();

        const int rowg = m0 + p * 32 + lr;
        const long long obase = cbase + (long long)rowg * N + n0 + cg;
        const f32x4 c4 = *(const f32x4*)(ldsC + lr * 132 + cg);
        f32x4 b4 = {0.0f, 0.0f, 0.0f, 0.0f};
        if (bias) b4 = *(const f32x4*)(bias + n0 + cg);
        f32x4 r4 = {0.0f, 0.0f, 0.0f, 0.0f};
        if (resF) r4 = *(const f32x4*)(resF + obase);
        else if (resB) {
            const u16x4 t = *(const u16x4*)(resB + obase);
#pragma unroll
            for (int q = 0; q < 4; ++q) r4[q] = b2f(t[q]);
        }
        u16 ob[4];
#pragma unroll
        for (int q = 0; q < 4; ++q) {
            float v = c4[q] + b4[q] + r4[q];
            if (do_swish) v = v * sigm_fast(v);
            if (partials) { sacc += v; ssacc = fmaf(v, v, ssacc); }
            ob[q] = f2b(v);
        }
        *(u16x4*)(outB + obase) = *(const u16x4*)(ob);
        __syncthreads();
    }

    if (partials) {
#pragma unroll
        for (int off = 32; off; off >>= 1) {
            sacc += __shfl_down(sacc, off);
            ssacc += __shfl_down(ssacc, off);
        }
        float* rs = ldsC + 6000;
        if ((tid & 63) == 0) { rs[wid] = sacc; rs[16 + wid] = ssacc; }
        __syncthreads();
        if (tid == 0) {
            float S = 0.0f, SS = 0.0f;
#pragma unroll
            for (int w = 0; w < 16; ++w) { S += rs[w]; SS += rs[16 + w]; }
            const int fb = (int)((blockIdx.z * gridDim.y + by) * gridDim.x + bx);
            partials[fb] = make_float2(S, SS);
        }
    }
}

// 1024 partials (32 per batch, batch-major) -> stats[b*2]={mu,rstd}. 1 block.
__global__ __launch_bounds__(1024) void stats_reduce(const float2* __restrict__ p,
                                                     float* __restrict__ st)
{
    const int tid = threadIdx.x;
    float2 v = p[tid];
    float s = v.x, ss = v.y;
#pragma unroll
    for (int off = 16; off; off >>= 1) {
        s += __shfl_down(s, off, 32);
        ss += __shfl_down(ss, off, 32);
    }
    if ((tid & 31) == 0) {
        const int b = tid >> 5;
        const float mu = s / 524288.0f;
        const float var = ss / 524288.0f - mu * mu;
        st[b * 2 + 0] = mu;
        st[b * 2 + 1] = rsqrtf(var + 1e-5f);
    }
}

// 4 fused fp32->bf16 transposes w[K][N] -> wt[N][K] (K=1024). block (32,8).
__global__ void prep_tr(const float* __restrict__ s0, const float* __restrict__ s1,
                        const float* __restrict__ s2, const float* __restrict__ s3,
                        u16* __restrict__ o0, u16* __restrict__ o1,
                        u16* __restrict__ o2, u16* __restrict__ o3)
{
    __shared__ float t[32][33];
    const int b = blockIdx.x;
    const float* src; u16* dst; int N, tt;
    if (b < 1024)      { src = s0; dst = o0; N = 1024; tt = b; }
    else if (b < 1536) { src = s1; dst = o1; N = 512;  tt = b - 1024; }
    else if (b < 2560) { src = s2; dst = o2; N = 1024; tt = b - 1536; }
    else               { src = s3; dst = o3; N = 512;  tt = b - 2560; }
    const int ntx = N >> 5;
    const int n0 = (tt % ntx) * 32, k0 = (tt / ntx) * 32;
    for (int i = threadIdx.y; i < 32; i += 8)
        t[i][threadIdx.x] = src[(long long)(k0 + i) * N + n0 + threadIdx.x];
    __syncthreads();
    for (int i = threadIdx.y; i < 32; i += 8)
        dst[(long long)(n0 + i) * 1024 + k0 + threadIdx.x] = f2b(t[threadIdx.x][i]);
}

// 4 fused fp32->bf16 casts. grid 1536 x 256.
__global__ void prep_cvt(const float* __restrict__ s0, const float* __restrict__ s1,
                         const float* __restrict__ s2, const float* __restrict__ s3,
                         u16* __restrict__ o0, u16* __restrict__ o1,
                         u16* __restrict__ o2, u16* __restrict__ o3)
{
    const int b = blockIdx.x;
    const float* src; u16* dst; long long off;
    if (b < 256)       { src = s0; dst = o0; off = (long long)b * 2048; }
    else if (b < 768)  { src = s1; dst = o1; off = (long long)(b - 256) * 2048; }
    else if (b < 1024) { src = s2; dst = o2; off = (long long)(b - 768) * 2048; }
    else               { src = s3; dst = o3; off = (long long)(b - 1024) * 2048; }
    const long long i = off + threadIdx.x * 8;
    const float4 a = *(const float4*)(src + i);
    const float4 c = *(const float4*)(src + i + 4);
    u16x8 o;
    o[0] = f2b(a.x); o[1] = f2b(a.y); o[2] = f2b(a.z); o[3] = f2b(a.w);
    o[4] = f2b(c.x); o[5] = f2b(c.y); o[6] = f2b(c.z); o[7] = f2b(c.w);
    *(u16x8*)(dst + i) = o;
}

// wq/wk/wv (4,512,64) fp32 -> qkvT[row=t*256+n*64+d][k=w] bf16 [768][512].
__global__ void qkvpack_kernel(const float* __restrict__ wq, const float* __restrict__ wk,
                               const float* __restrict__ wv, u16* __restrict__ out)
{
    const int o = blockIdx.x * 256 + threadIdx.x;  // 0..393215
    const int t = o >> 17;
    const int r = o & 131071;
    const int col = r >> 9;
    const int k = r & 511;
    const float* src = (t == 0) ? wq : (t == 1) ? wk : wv;
    out[o] = f2b(src[(col >> 6) * 32768 + k * 64 + (col & 63)]);
}

__global__ void biaspack_kernel(const float* __restrict__ bq, const float* __restrict__ bk,
                                const float* __restrict__ bv, float* __restrict__ out)
{
    const int i = blockIdx.x * 256 + threadIdx.x;  // 0..767
    const float* s = (i < 256) ? bq : (i < 512) ? bk : bv;
    out[i] = s[i & 255];
}

// fp32 -> bf16, 8 elems/thread.
__global__ void cvt_bf16_kernel(const float* __restrict__ in, u16* __restrict__ out)
{
    const long long i = ((long long)blockIdx.x * 256 + threadIdx.x) * 8;
    const float4 a = *(const float4*)(in + i);
    const float4 b = *(const float4*)(in + i + 4);
    u16x8 o;
    o[0] = f2b(a.x); o[1] = f2b(a.y); o[2] = f2b(a.z); o[3] = f2b(a.w);
    o[4] = f2b(b.x); o[5] = f2b(b.y); o[6] = f2b(b.z); o[7] = f2b(b.w);
    *(u16x8*)(out + i) = o;
}

// Column softmax over H=1024 on QKV [32768][768] bf16 (Q,K halves), in place.
__global__ __launch_bounds__(256) void softmax_qkv(u16* __restrict__ QKV, float sc)
{
    const int b = blockIdx.x;
    const int cbase = blockIdx.y * 64;
    const int pr = (threadIdx.x & 31) * 2;
    const int seg = threadIdx.x >> 5;
    u16* base = QKV + (long long)b * 786432 + cbase + pr;

    __shared__ float red_m[8][64];
    __shared__ float red_s[8][64];

    float m0 = -1e30f, m1 = -1e30f, s0 = 0.0f, s1 = 0.0f;
    for (int h = seg * 128; h < seg * 128 + 128; ++h) {
        const unsigned u = *(const unsigned*)(base + (long long)h * 768);
        const float v0 = b2f((u16)(u & 0xffff)) * sc;
        const float v1 = b2f((u16)(u >> 16)) * sc;
        const float nm0 = fmaxf(m0, v0), nm1 = fmaxf(m1, v1);
        s0 = s0 * __expf(m0 - nm0) + __expf(v0 - nm0);
        s1 = s1 * __expf(m1 - nm1) + __expf(v1 - nm1);
        m0 = nm0; m1 = nm1;
    }
    red_m[seg][pr] = m0; red_m[seg][pr + 1] = m1;
    red_s[seg][pr] = s0; red_s[seg][pr + 1] = s1;
    __syncthreads();

    float M0 = -1e30f, M1 = -1e30f;
#pragma unroll
    for (int s = 0; s < 8; ++s) { M0 = fmaxf(M0, red_m[s][pr]); M1 = fmaxf(M1, red_m[s][pr + 1]); }
    float S0 = 0.0f, S1 = 0.0f;
#pragma unroll
    for (int s = 0; s < 8; ++s) {
        S0 += red_s[s][pr] * __expf(red_m[s][pr] - M0);
        S1 += red_s[s][pr + 1] * __expf(red_m[s][pr + 1] - M1);
    }
    const float i0 = 1.0f / S0, i1 = 1.0f / S1;

    for (int h = seg * 128; h < seg * 128 + 128; ++h) {
        u16* p = base + (long long)h * 768;
        const unsigned u = *(const unsigned*)p;
        const float e0 = __expf(b2f((u16)(u & 0xffff)) * sc - M0) * i0;
        const float e1 = __expf(b2f((u16)(u >> 16)) * sc - M1) * i1;
        *(unsigned*)p = (unsigned)f2b(e0) | ((unsigned)f2b(e1) << 16);
    }
}

// Partial Bm over h-chunk: Part[c][b*4+n][d*64+e]. grid (128, 8).
__global__ __launch_bounds__(256) void bm_kernel(const u16* __restrict__ QKV,
                                                 float* __restrict__ Part)
{
    const int bx = blockIdx.x;            // b*4+n
    const int ch = blockIdx.y;            // 0..7 h-chunk of 128
    const int b = bx >> 2, n = bx & 3;
    const long long kbase = (long long)b * 786432 + 256 + n * 64;
    const long long vbase = (long long)b * 786432 + 512 + n * 64;
    __shared__ float Ks[64][64];
    __shared__ float Vs[64][64];
    const int tid = threadIdx.x;
    const int d = tid & 63, eg = tid >> 6;
    const int c4 = (tid & 15) * 4, rr = tid >> 4;
    float acc[16] = {};

    const int hbeg = ch * 128;
    for (int h0 = hbeg; h0 < hbeg + 128; h0 += 64) {
#pragma unroll
        for (int p = 0; p < 4; ++p) {
            const int hh = p * 16 + rr;
            const u16x4 kv = *(const u16x4*)(QKV + kbase + (long long)(h0 + hh) * 768 + c4);
            const u16x4 vv = *(const u16x4*)(QKV + vbase + (long long)(h0 + hh) * 768 + c4);
#pragma unroll
            for (int q = 0; q < 4; ++q) { Ks[hh][c4 + q] = b2f(kv[q]); Vs[hh][c4 + q] = b2f(vv[q]); }
        }
        __syncthreads();
        for (int hh = 0; hh < 64; ++hh) {
            const float kd = Ks[hh][d];
#pragma unroll
            for (int j = 0; j < 16; ++j)
                acc[j] = fmaf(kd, Vs[hh][eg * 16 + j], acc[j]);
        }
        __syncthreads();
    }
    float* o = Part + ((long long)ch * 128 + bx) * 4096 + d * 64 + eg * 16;
#pragma unroll
    for (int j = 0; j < 16; ++j) o[j] = acc[j];
}

// Bm[i] = sum_c Part[c][i]. 524288 elems, grid 2048 x 256.
__global__ void bm_reduce(const float* __restrict__ Part, float* __restrict__ Bm)
{
    const long long i = (long long)blockIdx.x * 256 + threadIdx.x;
    float s = 0.0f;
#pragma unroll
    for (int c = 0; c < 8; ++c) s += Part[(long long)c * 524288 + i];
    Bm[i] = s;
}

// W2t_att[b][w0+wl][n*64+d] = sum_e Bm[b,n,d,e] * wo[n*64+e][w]. grid (128, 8).
__global__ __launch_bounds__(256) void w2t_kernel(const float* __restrict__ Bm,
                                                  const float* __restrict__ wo,
                                                  u16* __restrict__ W2t)
{
    const int bx = blockIdx.x;            // b*4+n
    const int b = bx >> 2, n = bx & 3;
    const int w0 = blockIdx.y * 64;
    __shared__ float BmT[64][65];
    __shared__ float Ws[64][64];
    __shared__ float Ot[64][65];
    const int tid = threadIdx.x;
    const float* bm = Bm + (long long)bx * 4096;

    {
        const int e2 = tid & 63, r0 = (tid >> 6) * 16;
        for (int r = 0; r < 16; ++r)
            BmT[e2][r0 + r] = bm[(long long)(r0 + r) * 64 + e2];
    }
    {
        const int ww = tid & 63, r0 = (tid >> 6) * 16;
        for (int r = 0; r < 16; ++r)
            Ws[r0 + r][ww] = wo[(long long)(n * 64 + r0 + r) * 512 + w0 + ww];
    }
    __syncthreads();

    const int d = tid & 63, wg = tid >> 6;
    float acc[16] = {};
    for (int e = 0; e < 64; ++e) {
        const float bvv = BmT[e][d];
#pragma unroll
        for (int j = 0; j < 16; ++j)
            acc[j] = fmaf(bvv, Ws[e][wg * 16 + j], acc[j]);
    }
#pragma unroll
    for (int j = 0; j < 16; ++j) Ot[wg * 16 + j][d] = acc[j];
    __syncthreads();
    const int wl = tid >> 2, ds = (tid & 3) * 16;
    u16 tmp[16];
#pragma unroll
    for (int j = 0; j < 16; ++j) tmp[j] = f2b(Ot[wl][ds + j]);
    u16* op = W2t + (long long)b * 131072 + (long long)(w0 + wl) * 256 + n * 64 + ds;
    *(u16x8*)op = *(const u16x8*)tmp;
    *(u16x8*)(op + 8) = *(const u16x8*)(tmp + 8);
}

// Fused conv module on bf16 Xb in-place (fast sigmoid). grid 32*512, block 512.
__global__ __launch_bounds__(512) void conv_kernel(
    u16* __restrict__ Xb, const float* __restrict__ st,
    const float* __restrict__ ln1_g, const float* __restrict__ ln1_b,
    const float* __restrict__ pw1_w, const float* __restrict__ pw1_b,
    const float* __restrict__ dw1_w, const float* __restrict__ dw1_b,
    const float* __restrict__ dw2_w, const float* __restrict__ dw2_b,
    const float* __restrict__ bn_g, const float* __restrict__ bn_b,
    const float* __restrict__ bn_m, const float* __restrict__ bn_v,
    const float* __restrict__ pw2_w, const float* __restrict__ pw2_b)
{
    const int b = blockIdx.x >> 9;
    const int hr = blockIdx.x & 511;
    const int w = threadIdx.x;
    const long long base = (long long)b * 524288;
    const long long io = base + (long long)hr * 512 + w;
    const long long ig = base + (long long)(hr + 512) * 512 + w;

    const float mu = st[b * 2 + 0], rstd = st[b * 2 + 1];
    const float xo = b2f(Xb[io]), xg = b2f(Xb[ig]);
    const float p1w = pw1_w[0], p1b = pw1_b[0];

    const float yo = ((xo - mu) * rstd * ln1_g[hr * 512 + w] + ln1_b[hr * 512 + w]) * p1w + p1b;
    const float yg = ((xg - mu) * rstd * ln1_g[(hr + 512) * 512 + w] + ln1_b[(hr + 512) * 512 + w]) * p1w + p1b;

    __shared__ float gb[514];
    gb[w + 1] = yo * sigm_fast(yg);
    if (w == 0) { gb[0] = 0.0f; gb[513] = 0.0f; }
    __syncthreads();

    const float z = gb[w] * dw1_w[0] + gb[w + 1] * dw1_w[1] + gb[w + 2] * dw1_w[2] + dw1_b[0];
    const float bnscale = rsqrtf(bn_v[0] + 1e-5f);

    const float u0 = z * dw2_w[0] + dw2_b[0];
    const float v0 = (u0 - bn_m[0]) * bnscale * bn_g[0] + bn_b[0];
    const float p0 = (v0 * sigm_fast(v0)) * pw2_w[0] + pw2_b[0];

    const float u1 = z * dw2_w[1] + dw2_b[1];
    const float v1 = (u1 - bn_m[0]) * bnscale * bn_g[0] + bn_b[0];
    const float p1 = (v1 * sigm_fast(v1)) * pw2_w[0] + pw2_b[0];

    Xb[io] = f2b(xo + p0);
    Xb[ig] = f2b(xg + p1);
}

// out = inputs + ((Xb - mu_b) * rstd_b * lnf_g + lnf_b). 8 elems/thread. grid 8192.
__global__ void final_kernel(const float* __restrict__ inputs, const u16* __restrict__ Xb,
                             const float* __restrict__ st,
                             const float* __restrict__ lnf_g, const float* __restrict__ lnf_b,
                             float* __restrict__ out)
{
    const long long i = ((long long)blockIdx.x * 256 + threadIdx.x) * 8;
    const int b = (int)(i >> 19);
    const int r = (int)(i & 524287);
    const float mu = st[b * 2 + 0], rstd = st[b * 2 + 1];
    const u16x8 xv = *(const u16x8*)(Xb + i);
    float o[8];
#pragma unroll
    for (int q = 0; q < 8; ++q) o[q] = (b2f(xv[q]) - mu) * rstd;
    const float4 g0 = *(const float4*)(lnf_g + r);
    const float4 g1 = *(const float4*)(lnf_g + r + 4);
    const float4 c0 = *(const float4*)(lnf_b + r);
    const float4 c1 = *(const float4*)(lnf_b + r + 4);
    const float4 n0 = *(const float4*)(inputs + i);
    const float4 n1 = *(const float4*)(inputs + i + 4);
    float4 w0, w1;
    w0.x = n0.x + o[0] * g0.x + c0.x; w0.y = n0.y + o[1] * g0.y + c0.y;
    w0.z = n0.z + o[2] * g0.z + c0.z; w0.w = n0.w + o[3] * g0.w + c0.w;
    w1.x = n1.x + o[4] * g1.x + c1.x; w1.y = n1.y + o[5] * g1.y + c1.y;
    w1.z = n1.z + o[6] * g1.z + c1.z; w1.w = n1.w + o[7] * g1.w + c1.w;
    *(float4*)(out + i) = w0;
    *(float4*)(out + i + 4) = w1;
}

extern "C" void kernel_launch(void* const* d_in, const int* in_sizes, int n_in,
                              void* d_out, int out_size, void* d_ws, size_t ws_size,
                              hipStream_t stream)
{
    (void)in_sizes; (void)n_in; (void)out_size; (void)ws_size;

    const float* inp   = (const float*)d_in[0];
    const float* l1_e1 = (const float*)d_in[1];
    const float* l1_d1 = (const float*)d_in[2];
    const float* l1_e2 = (const float*)d_in[3];
    const float* l1_d2 = (const float*)d_in[4];
    const float* wq    = (const float*)d_in[5];
    const float* bq    = (const float*)d_in[6];
    const float* wk    = (const float*)d_in[7];
    const float* bk    = (const float*)d_in[8];
    const float* wv    = (const float*)d_in[9];
    const float* bv    = (const float*)d_in[10];
    const float* wo    = (const float*)d_in[11];
    const float* bo    = (const float*)d_in[12];
    const float* ln1_g = (const float*)d_in[13];
    const float* ln1_b = (const float*)d_in[14];
    const float* pw1_w = (const float*)d_in[15];
    const float* pw1_b = (const float*)d_in[16];
    const float* dw1_w = (const float*)d_in[17];
    const float* dw1_b = (const float*)d_in[18];
    const float* dw2_w = (const float*)d_in[19];
    const float* dw2_b = (const float*)d_in[20];
    const float* bn_g  = (const float*)d_in[21];
    const float* bn_b  = (const float*)d_in[22];
    const float* bn_m  = (const float*)d_in[23];
    const float* bn_v  = (const float*)d_in[24];
    const float* pw2_w = (const float*)d_in[25];
    const float* pw2_b = (const float*)d_in[26];
    const float* l2_e1 = (const float*)d_in[27];
    const float* l2_d1 = (const float*)d_in[28];
    const float* l2_e2 = (const float*)d_in[29];
    const float* l2_d2 = (const float*)d_in[30];
    const float* lnf_g = (const float*)d_in[31];
    const float* lnf_b = (const float*)d_in[32];

    char* wsb = (char*)d_ws;
    u16*   Xb = (u16*)(wsb);                           // 33,554,432 B
    char*  U  = wsb + 33554432;                        // 67,108,864 B union region

    // precompute-phase overlays in U (batched-fold-friendly strides)
    u16* l1_d1t = (u16*)(U + 0);                       // 2 MB [1024][1024]
    u16* l2_d1t = (u16*)(U + 2097152);                 // 2 MB
    u16* l1_d2t = (u16*)(U + 4194304);                 // 1 MB [512][1024]
    u16* l2_d2t = (u16*)(U + 5242880);                 // 1 MB
    u16* l1_e1b = (u16*)(U + 6291456);                 // 1 MB [512][1024]
    u16* l2_e1b = (u16*)(U + 7340032);                 // 1 MB
    u16* l1_e2b = (u16*)(U + 8388608);                 // 2 MB [1024][1024]
    u16* l2_e2b = (u16*)(U + 10485760);                // 2 MB
    // LFFN-phase overlay
    u16* H = (u16*)U;                                  // [32768][1024] bf16 (64 MB)
    // MHLA-phase overlays
    u16*   QKV    = (u16*)U;                           // [32768][768] bf16 (48 MB)
    u16*   W2t_at = (u16*)(U + 50331648);              // [32][512][256] bf16 (8 MB)
    float* Bm     = (float*)(U + 58720256);            // [32][4][64][64] fp32 (2 MB)

    // persistent region
    char* P = wsb + 100663296;
    u16*    W1t_l1  = (u16*)(P + 0);                   // [1024][512]
    u16*    W1t_l2  = (u16*)(P + 1048576);
    u16*    W2t_l1  = (u16*)(P + 2097152);             // [512][1024]
    u16*    W2t_l2  = (u16*)(P + 3145728);
    u16*    qkvT    = (u16*)(P + 4194304);             // [768][512]
    float*  qkvBias = (float*)(P + 4980736);           // 768
    float2* part0   = (float2*)(P + 4983808);          // 1024 float2
    float2* part1   = (float2*)(P + 4992000);
    float*  st0     = (float*)(P + 5000192);
    float*  st1     = (float*)(P + 5000448);
    float*  BmPart  = (float*)(P + 8388608);           // [8][128][4096] fp32 (16 MB)

    auto G = [&](const u16* A, const u16* Bt, u16* oB,
                 const float* resF, const u16* resB, const float* bias, float2* parts,
                 int M, int N, int K, int lda, float alpha, int sw,
                 long long sA, long long sB, long long sC, int nb) {
        dim3 grid(N / 128, M / 128, nb);
        gemm_bf16<<<grid, 1024, 0, stream>>>(A, Bt, oB, resF, resB, bias, parts,
                                             N, K, lda, alpha, sw, sA, sB, sC);
    };

    // ---- weight prep ----
    cvt_bf16_kernel<<<8192, 256, 0, stream>>>(inp, Xb);
    prep_tr<<<3072, dim3(32, 8), 0, stream>>>(l1_d1, l1_d2, l2_d1, l2_d2,
                                              l1_d1t, l1_d2t, l2_d1t, l2_d2t);
    prep_cvt<<<1536, 256, 0, stream>>>(l1_e1, l1_e2, l2_e1, l2_e2,
                                       l1_e1b, l1_e2b, l2_e1b, l2_e2b);
    qkvpack_kernel<<<1536, 256, 0, stream>>>(wq, wk, wv, qkvT);
    biaspack_kernel<<<3, 256, 0, stream>>>(bq, bk, bv, qkvBias);

    // ---- fold LFFN weight pairs (batched z=2): W1t = (e1@d1)^T, W2t = (e2@d2)^T
    G(l1_d1t, l1_e1b, W1t_l1, nullptr, nullptr, nullptr, nullptr,
      1024, 512, 1024, 1024, 1.0f, 0, 1048576LL, 524288LL, 524288LL, 2);
    G(l1_d2t, l1_e2b, W2t_l1, nullptr, nullptr, nullptr, nullptr,
      512, 1024, 1024, 1024, 1.0f, 0, 524288LL, 1048576LL, 524288LL, 2);

    // ---- LFFN1: Xb = inputs + 0.5 * (swish(x@W1) @ W2) ----
    G(Xb, W1t_l1, H, nullptr, nullptr, nullptr, nullptr, 32768, 1024, 512, 512, 1.0f, 1, 0, 0, 0, 1);
    G(H, W2t_l1, Xb, inp, nullptr, nullptr, nullptr, 32768, 512, 1024, 1024, 0.5f, 0, 0, 0, 0, 1);

    // ---- MHLA: Xb += Q_sm @ (Bm @ wo) + bo ----
    G(Xb, qkvT, QKV, nullptr, nullptr, qkvBias, nullptr, 32768, 768, 512, 512, 1.0f, 0, 0, 0, 0, 1);
    softmax_qkv<<<dim3(32, 8), 256, 0, stream>>>(QKV, 0.35355339059327373f);
    bm_kernel<<<dim3(128, 8), 256, 0, stream>>>(QKV, BmPart);
    bm_reduce<<<2048, 256, 0, stream>>>(BmPart, Bm);
    w2t_kernel<<<dim3(128, 8), 256, 0, stream>>>(Bm, wo, W2t_at);
    G(QKV, W2t_at, Xb, nullptr, Xb, bo, part0, 1024, 512, 256, 768, 1.0f, 0,
      786432LL, 131072LL, 524288LL, 32);
    stats_reduce<<<1, 1024, 0, stream>>>(part0, st0);

    // ---- Conv module: Xb += conv(Xb) ----
    conv_kernel<<<16384, 512, 0, stream>>>(Xb, st0, ln1_g, ln1_b, pw1_w, pw1_b,
                                           dw1_w, dw1_b, dw2_w, dw2_b,
                                           bn_g, bn_b, bn_m, bn_v, pw2_w, pw2_b);

    // ---- LFFN2: Xb = Xb + 0.5 * (swish(x@W1) @ W2), fused stats ----
    G(Xb, W1t_l2, H, nullptr, nullptr, nullptr, nullptr, 32768, 1024, 512, 512, 1.0f, 1, 0, 0, 0, 1);
    G(H, W2t_l2, Xb, nullptr, Xb, nullptr, part1, 32768, 512, 1024, 1024, 0.5f, 0, 0, 0, 0, 1);
    stats_reduce<<<1, 1024, 0, stream>>>(part1, st1);

    // ---- Final LN + residual ----
    final_kernel<<<8192, 256, 0, stream>>>(inp, Xb, st1, lnf_g, lnf_b, (float*)d_out);
}

// Round 21
// 462.879 us; speedup vs baseline: 1.0432x; 1.0432x over previous
//
#include <hip/hip_runtime.h>
#include <cstdint>

typedef unsigned short u16;
typedef short bf16x8 __attribute__((ext_vector_type(8)));
typedef float f32x4 __attribute__((ext_vector_type(4)));
typedef u16 u16x8 __attribute__((ext_vector_type(8)));
typedef u16 u16x4 __attribute__((ext_vector_type(4)));

// fast sigmoid: v_exp + v_rcp (free in the 512t GEMM epilogue: VGPR 52, LDS-bound occ).
static __device__ __forceinline__ float sigm_fast(float x) {
    return __builtin_amdgcn_rcpf(1.0f + __expf(-x));
}
static __device__ __forceinline__ float b2f(u16 u) {
    union { unsigned i; float f; } v; v.i = ((unsigned)u) << 16; return v.f;
}
static __device__ __forceinline__ u16 f2b(float f) {
    unsigned x = __float_as_uint(f);
    x = x + 0x7fffu + ((x >> 16) & 1u);
    return (u16)(x >> 16);
}
static __device__ __forceinline__ void gload16(const u16* g, u16* l) {
    __builtin_amdgcn_global_load_lds((__attribute__((address_space(1))) void*)(void*)g,
                                     (__attribute__((address_space(3))) void*)l, 16, 0, 0);
}

// ---------------------------------------------------------------------------
// bf16 MFMA GEMM — round-19 best (482 us; 512-thread optimum of the
// waves/SIMD dose-response: 2w=82us, 4w=54us, 8w=55us): 128x128 tile, BK=64,
// 512 threads (8 waves 2Mx4N, 64x32/wave), 64 KiB LDS double-buffer
// (2 blocks/CU -> 4 waves/SIMD), literal-buffer unrolled x2 K-loop,
// pre-swizzled global_load_lds, T1 XCD swizzle, fast-sigmoid epilogue,
// guarded stats.
// C = [swish](alpha * A @ Bt^T [+bias(col)] [+res]) -> bf16.
// ---------------------------------------------------------------------------
__global__ __launch_bounds__(512) void gemm_bf16(
    const u16* A, const u16* Bt, u16* outB,
    const float* resF, const u16* resB, const float* bias, float2* partials,
    int N, int K, int lda, float alpha, int do_swish,
    long long sA, long long sB, long long sC)
{
    __shared__ u16 lds[32768];  // 64 KB
    const int tid = threadIdx.x;
    const int lane = tid & 63;
    const int wid = tid >> 6;            // 0..7
    const int wm = wid >> 2;             // 0..1 -> rows wm*64..+64
    const int wn = wid & 3;              // 0..3 -> cols wn*32..+32

    // ---- T1: bijective XCD swizzle (requires nwg % 8 == 0, else identity) ----
    const int gx = gridDim.x, gy = gridDim.y;
    int flat = blockIdx.y * gx + blockIdx.x;
    const int nwg = gx * gy;
    if ((nwg & 7) == 0 && nwg >= 16) {
        const int q = nwg >> 3;
        flat = (flat & 7) * q + (flat >> 3);
    }
    const int bx = flat % gx;
    const int by = flat / gx;
    const int m0 = by * 128;
    const int n0 = bx * 128;
    const int bz = blockIdx.z;
    const long long cbase = (long long)bz * sC;

    const int srow = tid >> 3;   // 0..63
    const int sslot = tid & 7;   // 0..7

    f32x4 acc[4][2];
#pragma unroll
    for (int i = 0; i < 4; ++i)
#pragma unroll
        for (int j = 0; j < 2; ++j)
#pragma unroll
            for (int r = 0; r < 4; ++r) acc[i][j][r] = 0.0f;

    const u16* Abase = A + (long long)bz * sA + (long long)m0 * lda;
    const u16* Bbase = Bt + (long long)bz * sB + (long long)n0 * K;
    const int NT = K >> 6;   // even at all call sites (K in {256,512,1024})

    auto stage = [&](int buf, int kt) {   // buf literal at every call site
        const u16* Ab = Abase + kt * 64;
        const u16* Bb = Bbase + kt * 64;
        u16* LA = lds + buf * 16384;
        u16* LB = LA + 8192;
#pragma unroll
        for (int i = 0; i < 2; ++i) {
            const int row = srow + 64 * i;
            const int gs = (sslot ^ (row & 7)) * 8;
            gload16(Ab + (long long)row * lda + gs, LA + row * 64 + sslot * 8);
            gload16(Bb + (long long)row * K + gs, LB + row * 64 + sslot * 8);
        }
    };

    auto compute = [&](int buf) {         // buf literal at every call site
        const u16* LA = lds + buf * 16384;
        const u16* LB = LA + 8192;
#pragma unroll
        for (int ks = 0; ks < 2; ++ks) {
            bf16x8 av[4], bv[2];
            const int sl = ks * 4 + (lane >> 4);
#pragma unroll
            for (int i = 0; i < 4; ++i) {
                const int ar = wm * 64 + i * 16 + (lane & 15);
                av[i] = *(const bf16x8*)(LA + ar * 64 + (sl ^ (ar & 7)) * 8);
            }
#pragma unroll
            for (int j = 0; j < 2; ++j) {
                const int br = wn * 32 + j * 16 + (lane & 15);
                bv[j] = *(const bf16x8*)(LB + br * 64 + (sl ^ (br & 7)) * 8);
            }
#pragma unroll
            for (int i = 0; i < 4; ++i)
#pragma unroll
                for (int j = 0; j < 2; ++j)
                    acc[i][j] = __builtin_amdgcn_mfma_f32_16x16x32_bf16(av[i], bv[j], acc[i][j], 0, 0, 0);
        }
    };

    // ---- K-loop, unrolled x2: buffer indices are compile-time constants ----
    stage(0, 0);
    __syncthreads();
    for (int kt = 0; kt < NT; kt += 2) {
        if (kt + 1 < NT) stage(1, kt + 1);
        compute(0);
        __syncthreads();
        if (kt + 2 < NT) stage(0, kt + 2);
        compute(1);          // NT even -> buf1 always staged by this point
        __syncthreads();
    }
    // loop ends with __syncthreads -> LDS free for epilogue reuse

    // ---- epilogue: LDS bounce (fp32 [64][132] padded), two row-halves ----
    float* ldsC = (float*)lds;           // 64*132*4 = 33.8 KB
    float sacc = 0.0f, ssacc = 0.0f;
    const int lr = tid >> 3;             // 0..63 local row
    const int cg = (tid & 7) * 16;       // col group base (16 cols/thread)

#pragma unroll
    for (int p = 0; p < 2; ++p) {
        if (wm == p) {                    // 4 waves (wn=0..3) write their 64x32 slice
#pragma unroll
            for (int i = 0; i < 4; ++i)
#pragma unroll
                for (int j = 0; j < 2; ++j)
#pragma unroll
                    for (int r = 0; r < 4; ++r) {
                        const int rlo = i * 16 + ((lane >> 4) << 2) + r;     // 0..63
                        const int clo = wn * 32 + j * 16 + (lane & 15);      // 0..127
                        ldsC[rlo * 132 + clo] = alpha * acc[i][j][r];
                    }
        }
        __syncthreads();

        const int rowg = m0 + p * 64 + lr;
        const long long obase = cbase + (long long)rowg * N + n0 + cg;
        const float* lrow = ldsC + lr * 132 + cg;
        u16 ob[16];
#pragma unroll
        for (int k = 0; k < 4; ++k) {
            const f32x4 c4 = *(const f32x4*)(lrow + k * 4);
            f32x4 b4 = {0.0f, 0.0f, 0.0f, 0.0f};
            if (bias) b4 = *(const f32x4*)(bias + n0 + cg + k * 4);
            f32x4 r4 = {0.0f, 0.0f, 0.0f, 0.0f};
            if (resF) r4 = *(const f32x4*)(resF + obase + k * 4);
            else if (resB) {
                const u16x4 t = *(const u16x4*)(resB + obase + k * 4);
#pragma unroll
                for (int q = 0; q < 4; ++q) r4[q] = b2f(t[q]);
            }
#pragma unroll
            for (int q = 0; q < 4; ++q) {
                float v = c4[q] + b4[q] + r4[q];
                if (do_swish) v = v * sigm_fast(v);
                if (partials) { sacc += v; ssacc = fmaf(v, v, ssacc); }
                ob[k * 4 + q] = f2b(v);
            }
        }
        *(u16x8*)(outB + obase) = *(const u16x8*)(ob);
        *(u16x8*)(outB + obase + 8) = *(const u16x8*)(ob + 8);
        __syncthreads();
    }

    if (partials) {
#pragma unroll
        for (int off = 32; off; off >>= 1) {
            sacc += __shfl_down(sacc, off);
            ssacc += __shfl_down(ssacc, off);
        }
        float* rs = ldsC + 8448;
        if ((tid & 63) == 0) { rs[wid] = sacc; rs[8 + wid] = ssacc; }
        __syncthreads();
        if (tid == 0) {
            float S = 0.0f, SS = 0.0f;
#pragma unroll
            for (int w = 0; w < 8; ++w) { S += rs[w]; SS += rs[8 + w]; }
            const int fb = (int)((blockIdx.z * gridDim.y + by) * gridDim.x + bx);
            partials[fb] = make_float2(S, SS);
        }
    }
}

// 1024 partials (32 per batch, batch-major) -> stats[b*2]={mu,rstd}. 1 block.
__global__ __launch_bounds__(1024) void stats_reduce(const float2* __restrict__ p,
                                                     float* __restrict__ st)
{
    const int tid = threadIdx.x;
    float2 v = p[tid];
    float s = v.x, ss = v.y;
#pragma unroll
    for (int off = 16; off; off >>= 1) {
        s += __shfl_down(s, off, 32);
        ss += __shfl_down(ss, off, 32);
    }
    if ((tid & 31) == 0) {
        const int b = tid >> 5;
        const float mu = s / 524288.0f;
        const float var = ss / 524288.0f - mu * mu;
        st[b * 2 + 0] = mu;
        st[b * 2 + 1] = rsqrtf(var + 1e-5f);
    }
}

// 4 fused fp32->bf16 transposes w[K][N] -> wt[N][K] (K=1024). block (32,8).
__global__ void prep_tr(const float* __restrict__ s0, const float* __restrict__ s1,
                        const float* __restrict__ s2, const float* __restrict__ s3,
                        u16* __restrict__ o0, u16* __restrict__ o1,
                        u16* __restrict__ o2, u16* __restrict__ o3)
{
    __shared__ float t[32][33];
    const int b = blockIdx.x;
    const float* src; u16* dst; int N, tt;
    if (b < 1024)      { src = s0; dst = o0; N = 1024; tt = b; }
    else if (b < 1536) { src = s1; dst = o1; N = 512;  tt = b - 1024; }
    else if (b < 2560) { src = s2; dst = o2; N = 1024; tt = b - 1536; }
    else               { src = s3; dst = o3; N = 512;  tt = b - 2560; }
    const int ntx = N >> 5;
    const int n0 = (tt % ntx) * 32, k0 = (tt / ntx) * 32;
    for (int i = threadIdx.y; i < 32; i += 8)
        t[i][threadIdx.x] = src[(long long)(k0 + i) * N + n0 + threadIdx.x];
    __syncthreads();
    for (int i = threadIdx.y; i < 32; i += 8)
        dst[(long long)(n0 + i) * 1024 + k0 + threadIdx.x] = f2b(t[threadIdx.x][i]);
}

// 4 fused fp32->bf16 casts. grid 1536 x 256.
__global__ void prep_cvt(const float* __restrict__ s0, const float* __restrict__ s1,
                         const float* __restrict__ s2, const float* __restrict__ s3,
                         u16* __restrict__ o0, u16* __restrict__ o1,
                         u16* __restrict__ o2, u16* __restrict__ o3)
{
    const int b = blockIdx.x;
    const float* src; u16* dst; long long off;
    if (b < 256)       { src = s0; dst = o0; off = (long long)b * 2048; }
    else if (b < 768)  { src = s1; dst = o1; off = (long long)(b - 256) * 2048; }
    else if (b < 1024) { src = s2; dst = o2; off = (long long)(b - 768) * 2048; }
    else               { src = s3; dst = o3; off = (long long)(b - 1024) * 2048; }
    const long long i = off + threadIdx.x * 8;
    const float4 a = *(const float4*)(src + i);
    const float4 c = *(const float4*)(src + i + 4);
    u16x8 o;
    o[0] = f2b(a.x); o[1] = f2b(a.y); o[2] = f2b(a.z); o[3] = f2b(a.w);
    o[4] = f2b(c.x); o[5] = f2b(c.y); o[6] = f2b(c.z); o[7] = f2b(c.w);
    *(u16x8*)(dst + i) = o;
}

// wq/wk/wv (4,512,64) fp32 -> qkvT[row=t*256+n*64+d][k=w] bf16 [768][512].
__global__ void qkvpack_kernel(const float* __restrict__ wq, const float* __restrict__ wk,
                               const float* __restrict__ wv, u16* __restrict__ out)
{
    const int o = blockIdx.x * 256 + threadIdx.x;  // 0..393215
    const int t = o >> 17;
    const int r = o & 131071;
    const int col = r >> 9;
    const int k = r & 511;
    const float* src = (t == 0) ? wq : (t == 1) ? wk : wv;
    out[o] = f2b(src[(col >> 6) * 32768 + k * 64 + (col & 63)]);
}

__global__ void biaspack_kernel(const float* __restrict__ bq, const float* __restrict__ bk,
                                const float* __restrict__ bv, float* __restrict__ out)
{
    const int i = blockIdx.x * 256 + threadIdx.x;  // 0..767
    const float* s = (i < 256) ? bq : (i < 512) ? bk : bv;
    out[i] = s[i & 255];
}

// fp32 -> bf16, 8 elems/thread.
__global__ void cvt_bf16_kernel(const float* __restrict__ in, u16* __restrict__ out)
{
    const long long i = ((long long)blockIdx.x * 256 + threadIdx.x) * 8;
    const float4 a = *(const float4*)(in + i);
    const float4 b = *(const float4*)(in + i + 4);
    u16x8 o;
    o[0] = f2b(a.x); o[1] = f2b(a.y); o[2] = f2b(a.z); o[3] = f2b(a.w);
    o[4] = f2b(b.x); o[5] = f2b(b.y); o[6] = f2b(b.z); o[7] = f2b(b.w);
    *(u16x8*)(out + i) = o;
}

// Column softmax over H=1024 on QKV [32768][768] bf16 (Q,K halves), in place.
// ROUND-21: grid (32, 16), 32 cols/block, 16 segs x 64 rows -> 512 blocks
// (2 blocks/CU; was 256 @ 1/CU, latency-limited streaming).
__global__ __launch_bounds__(256) void softmax_qkv(u16* __restrict__ QKV, float sc)
{
    const int b = blockIdx.x;
    const int cbase = blockIdx.y * 32;
    const int pr = (threadIdx.x & 15) * 2;
    const int seg = threadIdx.x >> 4;     // 0..15
    u16* base = QKV + (long long)b * 786432 + cbase + pr;

    __shared__ float red_m[16][32];
    __shared__ float red_s[16][32];

    float m0 = -1e30f, m1 = -1e30f, s0 = 0.0f, s1 = 0.0f;
    for (int h = seg * 64; h < seg * 64 + 64; ++h) {
        const unsigned u = *(const unsigned*)(base + (long long)h * 768);
        const float v0 = b2f((u16)(u & 0xffff)) * sc;
        const float v1 = b2f((u16)(u >> 16)) * sc;
        const float nm0 = fmaxf(m0, v0), nm1 = fmaxf(m1, v1);
        s0 = s0 * __expf(m0 - nm0) + __expf(v0 - nm0);
        s1 = s1 * __expf(m1 - nm1) + __expf(v1 - nm1);
        m0 = nm0; m1 = nm1;
    }
    red_m[seg][pr] = m0; red_m[seg][pr + 1] = m1;
    red_s[seg][pr] = s0; red_s[seg][pr + 1] = s1;
    __syncthreads();

    float M0 = -1e30f, M1 = -1e30f;
#pragma unroll
    for (int s = 0; s < 16; ++s) { M0 = fmaxf(M0, red_m[s][pr]); M1 = fmaxf(M1, red_m[s][pr + 1]); }
    float S0 = 0.0f, S1 = 0.0f;
#pragma unroll
    for (int s = 0; s < 16; ++s) {
        S0 += red_s[s][pr] * __expf(red_m[s][pr] - M0);
        S1 += red_s[s][pr + 1] * __expf(red_m[s][pr + 1] - M1);
    }
    const float i0 = 1.0f / S0, i1 = 1.0f / S1;

    for (int h = seg * 64; h < seg * 64 + 64; ++h) {
        u16* p = base + (long long)h * 768;
        const unsigned u = *(const unsigned*)p;
        const float e0 = __expf(b2f((u16)(u & 0xffff)) * sc - M0) * i0;
        const float e1 = __expf(b2f((u16)(u >> 16)) * sc - M1) * i1;
        *(unsigned*)p = (unsigned)f2b(e0) | ((unsigned)f2b(e1) << 16);
    }
}

// Partial Bm over h-chunk: Part[c][b*4+n][d*64+e]. grid (128, 8).
__global__ __launch_bounds__(256) void bm_kernel(const u16* __restrict__ QKV,
                                                 float* __restrict__ Part)
{
    const int bx = blockIdx.x;            // b*4+n
    const int ch = blockIdx.y;            // 0..7 h-chunk of 128
    const int b = bx >> 2, n = bx & 3;
    const long long kbase = (long long)b * 786432 + 256 + n * 64;
    const long long vbase = (long long)b * 786432 + 512 + n * 64;
    __shared__ float Ks[64][64];
    __shared__ float Vs[64][64];
    const int tid = threadIdx.x;
    const int d = tid & 63, eg = tid >> 6;
    const int c4 = (tid & 15) * 4, rr = tid >> 4;
    float acc[16] = {};

    const int hbeg = ch * 128;
    for (int h0 = hbeg; h0 < hbeg + 128; h0 += 64) {
#pragma unroll
        for (int p = 0; p < 4; ++p) {
            const int hh = p * 16 + rr;
            const u16x4 kv = *(const u16x4*)(QKV + kbase + (long long)(h0 + hh) * 768 + c4);
            const u16x4 vv = *(const u16x4*)(QKV + vbase + (long long)(h0 + hh) * 768 + c4);
#pragma unroll
            for (int q = 0; q < 4; ++q) { Ks[hh][c4 + q] = b2f(kv[q]); Vs[hh][c4 + q] = b2f(vv[q]); }
        }
        __syncthreads();
        for (int hh = 0; hh < 64; ++hh) {
            const float kd = Ks[hh][d];
#pragma unroll
            for (int j = 0; j < 16; ++j)
                acc[j] = fmaf(kd, Vs[hh][eg * 16 + j], acc[j]);
        }
        __syncthreads();
    }
    float* o = Part + ((long long)ch * 128 + bx) * 4096 + d * 64 + eg * 16;
#pragma unroll
    for (int j = 0; j < 16; ++j) o[j] = acc[j];
}

// Bm[i] = sum_c Part[c][i]. 524288 elems, grid 2048 x 256.
__global__ void bm_reduce(const float* __restrict__ Part, float* __restrict__ Bm)
{
    const long long i = (long long)blockIdx.x * 256 + threadIdx.x;
    float s = 0.0f;
#pragma unroll
    for (int c = 0; c < 8; ++c) s += Part[(long long)c * 524288 + i];
    Bm[i] = s;
}

// W2t_att[b][w0+wl][n*64+d] = sum_e Bm[b,n,d,e] * wo[n*64+e][w]. grid (128, 8).
__global__ __launch_bounds__(256) void w2t_kernel(const float* __restrict__ Bm,
                                                  const float* __restrict__ wo,
                                                  u16* __restrict__ W2t)
{
    const int bx = blockIdx.x;            // b*4+n
    const int b = bx >> 2, n = bx & 3;
    const int w0 = blockIdx.y * 64;
    __shared__ float BmT[64][65];
    __shared__ float Ws[64][64];
    __shared__ float Ot[64][65];
    const int tid = threadIdx.x;
    const float* bm = Bm + (long long)bx * 4096;

    {
        const int e2 = tid & 63, r0 = (tid >> 6) * 16;
        for (int r = 0; r < 16; ++r)
            BmT[e2][r0 + r] = bm[(long long)(r0 + r) * 64 + e2];
    }
    {
        const int ww = tid & 63, r0 = (tid >> 6) * 16;
        for (int r = 0; r < 16; ++r)
            Ws[r0 + r][ww] = wo[(long long)(n * 64 + r0 + r) * 512 + w0 + ww];
    }
    __syncthreads();

    const int d = tid & 63, wg = tid >> 6;
    float acc[16] = {};
    for (int e = 0; e < 64; ++e) {
        const float bvv = BmT[e][d];
#pragma unroll
        for (int j = 0; j < 16; ++j)
            acc[j] = fmaf(bvv, Ws[e][wg * 16 + j], acc[j]);
    }
#pragma unroll
    for (int j = 0; j < 16; ++j) Ot[wg * 16 + j][d] = acc[j];
    __syncthreads();
    const int wl = tid >> 2, ds = (tid & 3) * 16;
    u16 tmp[16];
#pragma unroll
    for (int j = 0; j < 16; ++j) tmp[j] = f2b(Ot[wl][ds + j]);
    u16* op = W2t + (long long)b * 131072 + (long long)(w0 + wl) * 256 + n * 64 + ds;
    *(u16x8*)op = *(const u16x8*)tmp;
    *(u16x8*)(op + 8) = *(const u16x8*)(tmp + 8);
}

// Fused conv module on bf16 Xb in-place (fast sigmoid). grid 32*512, block 512.
__global__ __launch_bounds__(512) void conv_kernel(
    u16* __restrict__ Xb, const float* __restrict__ st,
    const float* __restrict__ ln1_g, const float* __restrict__ ln1_b,
    const float* __restrict__ pw1_w, const float* __restrict__ pw1_b,
    const float* __restrict__ dw1_w, const float* __restrict__ dw1_b,
    const float* __restrict__ dw2_w, const float* __restrict__ dw2_b,
    const float* __restrict__ bn_g, const float* __restrict__ bn_b,
    const float* __restrict__ bn_m, const float* __restrict__ bn_v,
    const float* __restrict__ pw2_w, const float* __restrict__ pw2_b)
{
    const int b = blockIdx.x >> 9;
    const int hr = blockIdx.x & 511;
    const int w = threadIdx.x;
    const long long base = (long long)b * 524288;
    const long long io = base + (long long)hr * 512 + w;
    const long long ig = base + (long long)(hr + 512) * 512 + w;

    const float mu = st[b * 2 + 0], rstd = st[b * 2 + 1];
    const float xo = b2f(Xb[io]), xg = b2f(Xb[ig]);
    const float p1w = pw1_w[0], p1b = pw1_b[0];

    const float yo = ((xo - mu) * rstd * ln1_g[hr * 512 + w] + ln1_b[hr * 512 + w]) * p1w + p1b;
    const float yg = ((xg - mu) * rstd * ln1_g[(hr + 512) * 512 + w] + ln1_b[(hr + 512) * 512 + w]) * p1w + p1b;

    __shared__ float gb[514];
    gb[w + 1] = yo * sigm_fast(yg);
    if (w == 0) { gb[0] = 0.0f; gb[513] = 0.0f; }
    __syncthreads();

    const float z = gb[w] * dw1_w[0] + gb[w + 1] * dw1_w[1] + gb[w + 2] * dw1_w[2] + dw1_b[0];
    const float bnscale = rsqrtf(bn_v[0] + 1e-5f);

    const float u0 = z * dw2_w[0] + dw2_b[0];
    const float v0 = (u0 - bn_m[0]) * bnscale * bn_g[0] + bn_b[0];
    const float p0 = (v0 * sigm_fast(v0)) * pw2_w[0] + pw2_b[0];

    const float u1 = z * dw2_w[1] + dw2_b[1];
    const float v1 = (u1 - bn_m[0]) * bnscale * bn_g[0] + bn_b[0];
    const float p1 = (v1 * sigm_fast(v1)) * pw2_w[0] + pw2_b[0];

    Xb[io] = f2b(xo + p0);
    Xb[ig] = f2b(xg + p1);
}

// out = inputs + ((Xb - mu_b) * rstd_b * lnf_g + lnf_b). 8 elems/thread. grid 8192.
__global__ void final_kernel(const float* __restrict__ inputs, const u16* __restrict__ Xb,
                             const float* __restrict__ st,
                             const float* __restrict__ lnf_g, const float* __restrict__ lnf_b,
                             float* __restrict__ out)
{
    const long long i = ((long long)blockIdx.x * 256 + threadIdx.x) * 8;
    const int b = (int)(i >> 19);
    const int r = (int)(i & 524287);
    const float mu = st[b * 2 + 0], rstd = st[b * 2 + 1];
    const u16x8 xv = *(const u16x8*)(Xb + i);
    float o[8];
#pragma unroll
    for (int q = 0; q < 8; ++q) o[q] = (b2f(xv[q]) - mu) * rstd;
    const float4 g0 = *(const float4*)(lnf_g + r);
    const float4 g1 = *(const float4*)(lnf_g + r + 4);
    const float4 c0 = *(const float4*)(lnf_b + r);
    const float4 c1 = *(const float4*)(lnf_b + r + 4);
    const float4 n0 = *(const float4*)(inputs + i);
    const float4 n1 = *(const float4*)(inputs + i + 4);
    float4 w0, w1;
    w0.x = n0.x + o[0] * g0.x + c0.x; w0.y = n0.y + o[1] * g0.y + c0.y;
    w0.z = n0.z + o[2] * g0.z + c0.z; w0.w = n0.w + o[3] * g0.w + c0.w;
    w1.x = n1.x + o[4] * g1.x + c1.x; w1.y = n1.y + o[5] * g1.y + c1.y;
    w1.z = n1.z + o[6] * g1.z + c1.z; w1.w = n1.w + o[7] * g1.w + c1.w;
    *(float4*)(out + i) = w0;
    *(float4*)(out + i + 4) = w1;
}

extern "C" void kernel_launch(void* const* d_in, const int* in_sizes, int n_in,
                              void* d_out, int out_size, void* d_ws, size_t ws_size,
                              hipStream_t stream)
{
    (void)in_sizes; (void)n_in; (void)out_size; (void)ws_size;

    const float* inp   = (const float*)d_in[0];
    const float* l1_e1 = (const float*)d_in[1];
    const float* l1_d1 = (const float*)d_in[2];
    const float* l1_e2 = (const float*)d_in[3];
    const float* l1_d2 = (const float*)d_in[4];
    const float* wq    = (const float*)d_in[5];
    const float* bq    = (const float*)d_in[6];
    const float* wk    = (const float*)d_in[7];
    const float* bk    = (const float*)d_in[8];
    const float* wv    = (const float*)d_in[9];
    const float* bv    = (const float*)d_in[10];
    const float* wo    = (const float*)d_in[11];
    const float* bo    = (const float*)d_in[12];
    const float* ln1_g = (const float*)d_in[13];
    const float* ln1_b = (const float*)d_in[14];
    const float* pw1_w = (const float*)d_in[15];
    const float* pw1_b = (const float*)d_in[16];
    const float* dw1_w = (const float*)d_in[17];
    const float* dw1_b = (const float*)d_in[18];
    const float* dw2_w = (const float*)d_in[19];
    const float* dw2_b = (const float*)d_in[20];
    const float* bn_g  = (const float*)d_in[21];
    const float* bn_b  = (const float*)d_in[22];
    const float* bn_m  = (const float*)d_in[23];
    const float* bn_v  = (const float*)d_in[24];
    const float* pw2_w = (const float*)d_in[25];
    const float* pw2_b = (const float*)d_in[26];
    const float* l2_e1 = (const float*)d_in[27];
    const float* l2_d1 = (const float*)d_in[28];
    const float* l2_e2 = (const float*)d_in[29];
    const float* l2_d2 = (const float*)d_in[30];
    const float* lnf_g = (const float*)d_in[31];
    const float* lnf_b = (const float*)d_in[32];

    char* wsb = (char*)d_ws;
    u16*   Xb = (u16*)(wsb);                           // 33,554,432 B
    char*  U  = wsb + 33554432;                        // 67,108,864 B union region

    // precompute-phase overlays in U (batched-fold-friendly strides)
    u16* l1_d1t = (u16*)(U + 0);                       // 2 MB [1024][1024]
    u16* l2_d1t = (u16*)(U + 2097152);                 // 2 MB
    u16* l1_d2t = (u16*)(U + 4194304);                 // 1 MB [512][1024]
    u16* l2_d2t = (u16*)(U + 5242880);                 // 1 MB
    u16* l1_e1b = (u16*)(U + 6291456);                 // 1 MB [512][1024]
    u16* l2_e1b = (u16*)(U + 7340032);                 // 1 MB
    u16* l1_e2b = (u16*)(U + 8388608);                 // 2 MB [1024][1024]
    u16* l2_e2b = (u16*)(U + 10485760);                // 2 MB
    // LFFN-phase overlay
    u16* H = (u16*)U;                                  // [32768][1024] bf16 (64 MB)
    // MHLA-phase overlays
    u16*   QKV    = (u16*)U;                           // [32768][768] bf16 (48 MB)
    u16*   W2t_at = (u16*)(U + 50331648);              // [32][512][256] bf16 (8 MB)
    float* Bm     = (float*)(U + 58720256);            // [32][4][64][64] fp32 (2 MB)

    // persistent region
    char* P = wsb + 100663296;
    u16*    W1t_l1  = (u16*)(P + 0);                   // [1024][512]
    u16*    W1t_l2  = (u16*)(P + 1048576);
    u16*    W2t_l1  = (u16*)(P + 2097152);             // [512][1024]
    u16*    W2t_l2  = (u16*)(P + 3145728);
    u16*    qkvT    = (u16*)(P + 4194304);             // [768][512]
    float*  qkvBias = (float*)(P + 4980736);           // 768
    float2* part0   = (float2*)(P + 4983808);          // 1024 float2
    float2* part1   = (float2*)(P + 4992000);
    float*  st0     = (float*)(P + 5000192);
    float*  st1     = (float*)(P + 5000448);
    float*  BmPart  = (float*)(P + 8388608);           // [8][128][4096] fp32 (16 MB)

    auto G = [&](const u16* A, const u16* Bt, u16* oB,
                 const float* resF, const u16* resB, const float* bias, float2* parts,
                 int M, int N, int K, int lda, float alpha, int sw,
                 long long sA, long long sB, long long sC, int nb) {
        dim3 grid(N / 128, M / 128, nb);
        gemm_bf16<<<grid, 512, 0, stream>>>(A, Bt, oB, resF, resB, bias, parts,
                                            N, K, lda, alpha, sw, sA, sB, sC);
    };

    // ---- weight prep ----
    cvt_bf16_kernel<<<8192, 256, 0, stream>>>(inp, Xb);
    prep_tr<<<3072, dim3(32, 8), 0, stream>>>(l1_d1, l1_d2, l2_d1, l2_d2,
                                              l1_d1t, l1_d2t, l2_d1t, l2_d2t);
    prep_cvt<<<1536, 256, 0, stream>>>(l1_e1, l1_e2, l2_e1, l2_e2,
                                       l1_e1b, l1_e2b, l2_e1b, l2_e2b);
    qkvpack_kernel<<<1536, 256, 0, stream>>>(wq, wk, wv, qkvT);
    biaspack_kernel<<<3, 256, 0, stream>>>(bq, bk, bv, qkvBias);

    // ---- fold LFFN weight pairs (batched z=2): W1t = (e1@d1)^T, W2t = (e2@d2)^T
    G(l1_d1t, l1_e1b, W1t_l1, nullptr, nullptr, nullptr, nullptr,
      1024, 512, 1024, 1024, 1.0f, 0, 1048576LL, 524288LL, 524288LL, 2);
    G(l1_d2t, l1_e2b, W2t_l1, nullptr, nullptr, nullptr, nullptr,
      512, 1024, 1024, 1024, 1.0f, 0, 524288LL, 1048576LL, 524288LL, 2);

    // ---- LFFN1: Xb = inputs + 0.5 * (swish(x@W1) @ W2) ----
    G(Xb, W1t_l1, H, nullptr, nullptr, nullptr, nullptr, 32768, 1024, 512, 512, 1.0f, 1, 0, 0, 0, 1);
    G(H, W2t_l1, Xb, inp, nullptr, nullptr, nullptr, 32768, 512, 1024, 1024, 0.5f, 0, 0, 0, 0, 1);

    // ---- MHLA: Xb += Q_sm @ (Bm @ wo) + bo ----
    G(Xb, qkvT, QKV, nullptr, nullptr, qkvBias, nullptr, 32768, 768, 512, 512, 1.0f, 0, 0, 0, 0, 1);
    softmax_qkv<<<dim3(32, 16), 256, 0, stream>>>(QKV, 0.35355339059327373f);
    bm_kernel<<<dim3(128, 8), 256, 0, stream>>>(QKV, BmPart);
    bm_reduce<<<2048, 256, 0, stream>>>(BmPart, Bm);
    w2t_kernel<<<dim3(128, 8), 256, 0, stream>>>(Bm, wo, W2t_at);
    G(QKV, W2t_at, Xb, nullptr, Xb, bo, part0, 1024, 512, 256, 768, 1.0f, 0,
      786432LL, 131072LL, 524288LL, 32);
    stats_reduce<<<1, 1024, 0, stream>>>(part0, st0);

    // ---- Conv module: Xb += conv(Xb) ----
    conv_kernel<<<16384, 512, 0, stream>>>(Xb, st0, ln1_g, ln1_b, pw1_w, pw1_b,
                                           dw1_w, dw1_b, dw2_w, dw2_b,
                                           bn_g, bn_b, bn_m, bn_v, pw2_w, pw2_b);

    // ---- LFFN2: Xb = Xb + 0.5 * (swish(x@W1) @ W2), fused stats ----
    G(Xb, W1t_l2, H, nullptr, nullptr, nullptr, nullptr, 32768, 1024, 512, 512, 1.0f, 1, 0, 0, 0, 1);
    G(H, W2t_l2, Xb, nullptr, Xb, nullptr, part1, 32768, 512, 1024, 1024, 0.5f, 0, 0, 0, 0, 1);
    stats_reduce<<<1, 1024, 0, stream>>>(part1, st1);

    // ---- Final LN + residual ----
    final_kernel<<<8192, 256, 0, stream>>>(inp, Xb, st1, lnf_g, lnf_b, (float*)d_out);
}

// Round 22
// 461.835 us; speedup vs baseline: 1.0455x; 1.0023x over previous
//
#include <hip/hip_runtime.h>
#include <cstdint>

typedef unsigned short u16;
typedef short bf16x8 __attribute__((ext_vector_type(8)));
typedef float f32x4 __attribute__((ext_vector_type(4)));
typedef u16 u16x8 __attribute__((ext_vector_type(8)));
typedef u16 u16x4 __attribute__((ext_vector_type(4)));

// fast sigmoid: v_exp + v_rcp (free in the 512t GEMM epilogue: VGPR 52, LDS-bound occ).
static __device__ __forceinline__ float sigm_fast(float x) {
    return __builtin_amdgcn_rcpf(1.0f + __expf(-x));
}
static __device__ __forceinline__ float b2f(u16 u) {
    union { unsigned i; float f; } v; v.i = ((unsigned)u) << 16; return v.f;
}
static __device__ __forceinline__ u16 f2b(float f) {
    unsigned x = __float_as_uint(f);
    x = x + 0x7fffu + ((x >> 16) & 1u);
    return (u16)(x >> 16);
}
static __device__ __forceinline__ void gload16(const u16* g, u16* l) {
    __builtin_amdgcn_global_load_lds((__attribute__((address_space(1))) void*)(void*)g,
                                     (__attribute__((address_space(3))) void*)l, 16, 0, 0);
}

// ---------------------------------------------------------------------------
// bf16 MFMA GEMM — session-final config (round 19/21): 128x128 tile, BK=64,
// 512 threads (8 waves 2Mx4N, 64x32/wave; waves/SIMD dose-response optimum:
// 2w=82us, 4w=54us, 8w=55us), 64 KiB LDS double-buffer (2 blocks/CU ->
// 4 waves/SIMD), literal-buffer unrolled x2 K-loop, pre-swizzled
// global_load_lds, T1 XCD swizzle, fast-sigmoid epilogue, guarded stats.
// Effective ~632 TF = 93% of the measured 2-phase-128^2 structural ceiling
// (m230: 682 TF); further FLOP/LDS-byte needs 96KB tiles -> 1 block/CU (bad).
// C = [swish](alpha * A @ Bt^T [+bias(col)] [+res]) -> bf16.
// ---------------------------------------------------------------------------
__global__ __launch_bounds__(512) void gemm_bf16(
    const u16* A, const u16* Bt, u16* outB,
    const float* resF, const u16* resB, const float* bias, float2* partials,
    int N, int K, int lda, float alpha, int do_swish,
    long long sA, long long sB, long long sC)
{
    __shared__ u16 lds[32768];  // 64 KB
    const int tid = threadIdx.x;
    const int lane = tid & 63;
    const int wid = tid >> 6;            // 0..7
    const int wm = wid >> 2;             // 0..1 -> rows wm*64..+64
    const int wn = wid & 3;              // 0..3 -> cols wn*32..+32

    // ---- T1: bijective XCD swizzle (requires nwg % 8 == 0, else identity) ----
    const int gx = gridDim.x, gy = gridDim.y;
    int flat = blockIdx.y * gx + blockIdx.x;
    const int nwg = gx * gy;
    if ((nwg & 7) == 0 && nwg >= 16) {
        const int q = nwg >> 3;
        flat = (flat & 7) * q + (flat >> 3);
    }
    const int bx = flat % gx;
    const int by = flat / gx;
    const int m0 = by * 128;
    const int n0 = bx * 128;
    const int bz = blockIdx.z;
    const long long cbase = (long long)bz * sC;

    const int srow = tid >> 3;   // 0..63
    const int sslot = tid & 7;   // 0..7

    f32x4 acc[4][2];
#pragma unroll
    for (int i = 0; i < 4; ++i)
#pragma unroll
        for (int j = 0; j < 2; ++j)
#pragma unroll
            for (int r = 0; r < 4; ++r) acc[i][j][r] = 0.0f;

    const u16* Abase = A + (long long)bz * sA + (long long)m0 * lda;
    const u16* Bbase = Bt + (long long)bz * sB + (long long)n0 * K;
    const int NT = K >> 6;   // even at all call sites (K in {256,512,1024})

    auto stage = [&](int buf, int kt) {   // buf literal at every call site
        const u16* Ab = Abase + kt * 64;
        const u16* Bb = Bbase + kt * 64;
        u16* LA = lds + buf * 16384;
        u16* LB = LA + 8192;
#pragma unroll
        for (int i = 0; i < 2; ++i) {
            const int row = srow + 64 * i;
            const int gs = (sslot ^ (row & 7)) * 8;
            gload16(Ab + (long long)row * lda + gs, LA + row * 64 + sslot * 8);
            gload16(Bb + (long long)row * K + gs, LB + row * 64 + sslot * 8);
        }
    };

    auto compute = [&](int buf) {         // buf literal at every call site
        const u16* LA = lds + buf * 16384;
        const u16* LB = LA + 8192;
#pragma unroll
        for (int ks = 0; ks < 2; ++ks) {
            bf16x8 av[4], bv[2];
            const int sl = ks * 4 + (lane >> 4);
#pragma unroll
            for (int i = 0; i < 4; ++i) {
                const int ar = wm * 64 + i * 16 + (lane & 15);
                av[i] = *(const bf16x8*)(LA + ar * 64 + (sl ^ (ar & 7)) * 8);
            }
#pragma unroll
            for (int j = 0; j < 2; ++j) {
                const int br = wn * 32 + j * 16 + (lane & 15);
                bv[j] = *(const bf16x8*)(LB + br * 64 + (sl ^ (br & 7)) * 8);
            }
#pragma unroll
            for (int i = 0; i < 4; ++i)
#pragma unroll
                for (int j = 0; j < 2; ++j)
                    acc[i][j] = __builtin_amdgcn_mfma_f32_16x16x32_bf16(av[i], bv[j], acc[i][j], 0, 0, 0);
        }
    };

    // ---- K-loop, unrolled x2: buffer indices are compile-time constants ----
    stage(0, 0);
    __syncthreads();
    for (int kt = 0; kt < NT; kt += 2) {
        if (kt + 1 < NT) stage(1, kt + 1);
        compute(0);
        __syncthreads();
        if (kt + 2 < NT) stage(0, kt + 2);
        compute(1);          // NT even -> buf1 always staged by this point
        __syncthreads();
    }
    // loop ends with __syncthreads -> LDS free for epilogue reuse

    // ---- epilogue: LDS bounce (fp32 [64][132] padded), two row-halves ----
    float* ldsC = (float*)lds;           // 64*132*4 = 33.8 KB
    float sacc = 0.0f, ssacc = 0.0f;
    const int lr = tid >> 3;             // 0..63 local row
    const int cg = (tid & 7) * 16;       // col group base (16 cols/thread)

#pragma unroll
    for (int p = 0; p < 2; ++p) {
        if (wm == p) {                    // 4 waves (wn=0..3) write their 64x32 slice
#pragma unroll
            for (int i = 0; i < 4; ++i)
#pragma unroll
                for (int j = 0; j < 2; ++j)
#pragma unroll
                    for (int r = 0; r < 4; ++r) {
                        const int rlo = i * 16 + ((lane >> 4) << 2) + r;     // 0..63
                        const int clo = wn * 32 + j * 16 + (lane & 15);      // 0..127
                        ldsC[rlo * 132 + clo] = alpha * acc[i][j][r];
                    }
        }
        __syncthreads();

        const int rowg = m0 + p * 64 + lr;
        const long long obase = cbase + (long long)rowg * N + n0 + cg;
        const float* lrow = ldsC + lr * 132 + cg;
        u16 ob[16];
#pragma unroll
        for (int k = 0; k < 4; ++k) {
            const f32x4 c4 = *(const f32x4*)(lrow + k * 4);
            f32x4 b4 = {0.0f, 0.0f, 0.0f, 0.0f};
            if (bias) b4 = *(const f32x4*)(bias + n0 + cg + k * 4);
            f32x4 r4 = {0.0f, 0.0f, 0.0f, 0.0f};
            if (resF) r4 = *(const f32x4*)(resF + obase + k * 4);
            else if (resB) {
                const u16x4 t = *(const u16x4*)(resB + obase + k * 4);
#pragma unroll
                for (int q = 0; q < 4; ++q) r4[q] = b2f(t[q]);
            }
#pragma unroll
            for (int q = 0; q < 4; ++q) {
                float v = c4[q] + b4[q] + r4[q];
                if (do_swish) v = v * sigm_fast(v);
                if (partials) { sacc += v; ssacc = fmaf(v, v, ssacc); }
                ob[k * 4 + q] = f2b(v);
            }
        }
        *(u16x8*)(outB + obase) = *(const u16x8*)(ob);
        *(u16x8*)(outB + obase + 8) = *(const u16x8*)(ob + 8);
        __syncthreads();
    }

    if (partials) {
#pragma unroll
        for (int off = 32; off; off >>= 1) {
            sacc += __shfl_down(sacc, off);
            ssacc += __shfl_down(ssacc, off);
        }
        float* rs = ldsC + 8448;
        if ((tid & 63) == 0) { rs[wid] = sacc; rs[8 + wid] = ssacc; }
        __syncthreads();
        if (tid == 0) {
            float S = 0.0f, SS = 0.0f;
#pragma unroll
            for (int w = 0; w < 8; ++w) { S += rs[w]; SS += rs[8 + w]; }
            const int fb = (int)((blockIdx.z * gridDim.y + by) * gridDim.x + bx);
            partials[fb] = make_float2(S, SS);
        }
    }
}

// 4 fused fp32->bf16 transposes w[K][N] -> wt[N][K] (K=1024). block (32,8).
__global__ void prep_tr(const float* __restrict__ s0, const float* __restrict__ s1,
                        const float* __restrict__ s2, const float* __restrict__ s3,
                        u16* __restrict__ o0, u16* __restrict__ o1,
                        u16* __restrict__ o2, u16* __restrict__ o3)
{
    __shared__ float t[32][33];
    const int b = blockIdx.x;
    const float* src; u16* dst; int N, tt;
    if (b < 1024)      { src = s0; dst = o0; N = 1024; tt = b; }
    else if (b < 1536) { src = s1; dst = o1; N = 512;  tt = b - 1024; }
    else if (b < 2560) { src = s2; dst = o2; N = 1024; tt = b - 1536; }
    else               { src = s3; dst = o3; N = 512;  tt = b - 2560; }
    const int ntx = N >> 5;
    const int n0 = (tt % ntx) * 32, k0 = (tt / ntx) * 32;
    for (int i = threadIdx.y; i < 32; i += 8)
        t[i][threadIdx.x] = src[(long long)(k0 + i) * N + n0 + threadIdx.x];
    __syncthreads();
    for (int i = threadIdx.y; i < 32; i += 8)
        dst[(long long)(n0 + i) * 1024 + k0 + threadIdx.x] = f2b(t[threadIdx.x][i]);
}

// 4 fused fp32->bf16 casts. grid 1536 x 256.
__global__ void prep_cvt(const float* __restrict__ s0, const float* __restrict__ s1,
                         const float* __restrict__ s2, const float* __restrict__ s3,
                         u16* __restrict__ o0, u16* __restrict__ o1,
                         u16* __restrict__ o2, u16* __restrict__ o3)
{
    const int b = blockIdx.x;
    const float* src; u16* dst; long long off;
    if (b < 256)       { src = s0; dst = o0; off = (long long)b * 2048; }
    else if (b < 768)  { src = s1; dst = o1; off = (long long)(b - 256) * 2048; }
    else if (b < 1024) { src = s2; dst = o2; off = (long long)(b - 768) * 2048; }
    else               { src = s3; dst = o3; off = (long long)(b - 1024) * 2048; }
    const long long i = off + threadIdx.x * 8;
    const float4 a = *(const float4*)(src + i);
    const float4 c = *(const float4*)(src + i + 4);
    u16x8 o;
    o[0] = f2b(a.x); o[1] = f2b(a.y); o[2] = f2b(a.z); o[3] = f2b(a.w);
    o[4] = f2b(c.x); o[5] = f2b(c.y); o[6] = f2b(c.z); o[7] = f2b(c.w);
    *(u16x8*)(dst + i) = o;
}

// wq/wk/wv (4,512,64) fp32 -> qkvT[row=t*256+n*64+d][k=w] bf16 [768][512].
__global__ void qkvpack_kernel(const float* __restrict__ wq, const float* __restrict__ wk,
                               const float* __restrict__ wv, u16* __restrict__ out)
{
    const int o = blockIdx.x * 256 + threadIdx.x;  // 0..393215
    const int t = o >> 17;
    const int r = o & 131071;
    const int col = r >> 9;
    const int k = r & 511;
    const float* src = (t == 0) ? wq : (t == 1) ? wk : wv;
    out[o] = f2b(src[(col >> 6) * 32768 + k * 64 + (col & 63)]);
}

__global__ void biaspack_kernel(const float* __restrict__ bq, const float* __restrict__ bk,
                                const float* __restrict__ bv, float* __restrict__ out)
{
    const int i = blockIdx.x * 256 + threadIdx.x;  // 0..767
    const float* s = (i < 256) ? bq : (i < 512) ? bk : bv;
    out[i] = s[i & 255];
}

// fp32 -> bf16, 8 elems/thread.
__global__ void cvt_bf16_kernel(const float* __restrict__ in, u16* __restrict__ out)
{
    const long long i = ((long long)blockIdx.x * 256 + threadIdx.x) * 8;
    const float4 a = *(const float4*)(in + i);
    const float4 b = *(const float4*)(in + i + 4);
    u16x8 o;
    o[0] = f2b(a.x); o[1] = f2b(a.y); o[2] = f2b(a.z); o[3] = f2b(a.w);
    o[4] = f2b(b.x); o[5] = f2b(b.y); o[6] = f2b(b.z); o[7] = f2b(b.w);
    *(u16x8*)(out + i) = o;
}

// Column softmax over H=1024 on QKV [32768][768] bf16 (Q,K halves), in place.
// grid (32, 16), 32 cols/block, 16 segs x 64 rows -> 512 blocks (2/CU).
__global__ __launch_bounds__(256) void softmax_qkv(u16* __restrict__ QKV, float sc)
{
    const int b = blockIdx.x;
    const int cbase = blockIdx.y * 32;
    const int pr = (threadIdx.x & 15) * 2;
    const int seg = threadIdx.x >> 4;     // 0..15
    u16* base = QKV + (long long)b * 786432 + cbase + pr;

    __shared__ float red_m[16][32];
    __shared__ float red_s[16][32];

    float m0 = -1e30f, m1 = -1e30f, s0 = 0.0f, s1 = 0.0f;
    for (int h = seg * 64; h < seg * 64 + 64; ++h) {
        const unsigned u = *(const unsigned*)(base + (long long)h * 768);
        const float v0 = b2f((u16)(u & 0xffff)) * sc;
        const float v1 = b2f((u16)(u >> 16)) * sc;
        const float nm0 = fmaxf(m0, v0), nm1 = fmaxf(m1, v1);
        s0 = s0 * __expf(m0 - nm0) + __expf(v0 - nm0);
        s1 = s1 * __expf(m1 - nm1) + __expf(v1 - nm1);
        m0 = nm0; m1 = nm1;
    }
    red_m[seg][pr] = m0; red_m[seg][pr + 1] = m1;
    red_s[seg][pr] = s0; red_s[seg][pr + 1] = s1;
    __syncthreads();

    float M0 = -1e30f, M1 = -1e30f;
#pragma unroll
    for (int s = 0; s < 16; ++s) { M0 = fmaxf(M0, red_m[s][pr]); M1 = fmaxf(M1, red_m[s][pr + 1]); }
    float S0 = 0.0f, S1 = 0.0f;
#pragma unroll
    for (int s = 0; s < 16; ++s) {
        S0 += red_s[s][pr] * __expf(red_m[s][pr] - M0);
        S1 += red_s[s][pr + 1] * __expf(red_m[s][pr + 1] - M1);
    }
    const float i0 = 1.0f / S0, i1 = 1.0f / S1;

    for (int h = seg * 64; h < seg * 64 + 64; ++h) {
        u16* p = base + (long long)h * 768;
        const unsigned u = *(const unsigned*)p;
        const float e0 = __expf(b2f((u16)(u & 0xffff)) * sc - M0) * i0;
        const float e1 = __expf(b2f((u16)(u >> 16)) * sc - M1) * i1;
        *(unsigned*)p = (unsigned)f2b(e0) | ((unsigned)f2b(e1) << 16);
    }
}

// Partial Bm over h-chunk: Part[c][b*4+n][d*64+e]. grid (128, 8).
__global__ __launch_bounds__(256) void bm_kernel(const u16* __restrict__ QKV,
                                                 float* __restrict__ Part)
{
    const int bx = blockIdx.x;            // b*4+n
    const int ch = blockIdx.y;            // 0..7 h-chunk of 128
    const int b = bx >> 2, n = bx & 3;
    const long long kbase = (long long)b * 786432 + 256 + n * 64;
    const long long vbase = (long long)b * 786432 + 512 + n * 64;
    __shared__ float Ks[64][64];
    __shared__ float Vs[64][64];
    const int tid = threadIdx.x;
    const int d = tid & 63, eg = tid >> 6;
    const int c4 = (tid & 15) * 4, rr = tid >> 4;
    float acc[16] = {};

    const int hbeg = ch * 128;
    for (int h0 = hbeg; h0 < hbeg + 128; h0 += 64) {
#pragma unroll
        for (int p = 0; p < 4; ++p) {
            const int hh = p * 16 + rr;
            const u16x4 kv = *(const u16x4*)(QKV + kbase + (long long)(h0 + hh) * 768 + c4);
            const u16x4 vv = *(const u16x4*)(QKV + vbase + (long long)(h0 + hh) * 768 + c4);
#pragma unroll
            for (int q = 0; q < 4; ++q) { Ks[hh][c4 + q] = b2f(kv[q]); Vs[hh][c4 + q] = b2f(vv[q]); }
        }
        __syncthreads();
        for (int hh = 0; hh < 64; ++hh) {
            const float kd = Ks[hh][d];
#pragma unroll
            for (int j = 0; j < 16; ++j)
                acc[j] = fmaf(kd, Vs[hh][eg * 16 + j], acc[j]);
        }
        __syncthreads();
    }
    float* o = Part + ((long long)ch * 128 + bx) * 4096 + d * 64 + eg * 16;
#pragma unroll
    for (int j = 0; j < 16; ++j) o[j] = acc[j];
}

// Bm[i] = sum_c Part[c][i]. 524288 elems, grid 2048 x 256.
__global__ void bm_reduce(const float* __restrict__ Part, float* __restrict__ Bm)
{
    const long long i = (long long)blockIdx.x * 256 + threadIdx.x;
    float s = 0.0f;
#pragma unroll
    for (int c = 0; c < 8; ++c) s += Part[(long long)c * 524288 + i];
    Bm[i] = s;
}

// W2t_att[b][w0+wl][n*64+d] = sum_e Bm[b,n,d,e] * wo[n*64+e][w]. grid (128, 8).
__global__ __launch_bounds__(256) void w2t_kernel(const float* __restrict__ Bm,
                                                  const float* __restrict__ wo,
                                                  u16* __restrict__ W2t)
{
    const int bx = blockIdx.x;            // b*4+n
    const int b = bx >> 2, n = bx & 3;
    const int w0 = blockIdx.y * 64;
    __shared__ float BmT[64][65];
    __shared__ float Ws[64][64];
    __shared__ float Ot[64][65];
    const int tid = threadIdx.x;
    const float* bm = Bm + (long long)bx * 4096;

    {
        const int e2 = tid & 63, r0 = (tid >> 6) * 16;
        for (int r = 0; r < 16; ++r)
            BmT[e2][r0 + r] = bm[(long long)(r0 + r) * 64 + e2];
    }
    {
        const int ww = tid & 63, r0 = (tid >> 6) * 16;
        for (int r = 0; r < 16; ++r)
            Ws[r0 + r][ww] = wo[(long long)(n * 64 + r0 + r) * 512 + w0 + ww];
    }
    __syncthreads();

    const int d = tid & 63, wg = tid >> 6;
    float acc[16] = {};
    for (int e = 0; e < 64; ++e) {
        const float bvv = BmT[e][d];
#pragma unroll
        for (int j = 0; j < 16; ++j)
            acc[j] = fmaf(bvv, Ws[e][wg * 16 + j], acc[j]);
    }
#pragma unroll
    for (int j = 0; j < 16; ++j) Ot[wg * 16 + j][d] = acc[j];
    __syncthreads();
    const int wl = tid >> 2, ds = (tid & 3) * 16;
    u16 tmp[16];
#pragma unroll
    for (int j = 0; j < 16; ++j) tmp[j] = f2b(Ot[wl][ds + j]);
    u16* op = W2t + (long long)b * 131072 + (long long)(w0 + wl) * 256 + n * 64 + ds;
    *(u16x8*)op = *(const u16x8*)tmp;
    *(u16x8*)(op + 8) = *(const u16x8*)(tmp + 8);
}

// Fused conv module on bf16 Xb in-place. ROUND-22: per-block inline stats
// reduction over the batch's 32 contiguous GEMM partials (replaces the
// serial 1-block stats_reduce dispatch; 32 L2 loads + 5 shuffles per block).
// grid 32*512 (b,hr), block 512 (w).
__global__ __launch_bounds__(512) void conv_kernel(
    u16* __restrict__ Xb, const float2* __restrict__ part,
    const float* __restrict__ ln1_g, const float* __restrict__ ln1_b,
    const float* __restrict__ pw1_w, const float* __restrict__ pw1_b,
    const float* __restrict__ dw1_w, const float* __restrict__ dw1_b,
    const float* __restrict__ dw2_w, const float* __restrict__ dw2_b,
    const float* __restrict__ bn_g, const float* __restrict__ bn_b,
    const float* __restrict__ bn_m, const float* __restrict__ bn_v,
    const float* __restrict__ pw2_w, const float* __restrict__ pw2_b)
{
    const int b = blockIdx.x >> 9;
    const int hr = blockIdx.x & 511;
    const int w = threadIdx.x;

    __shared__ float smu, srstd;
    if (w < 32) {
        const float2 v = part[b * 32 + w];
        float s = v.x, ss = v.y;
#pragma unroll
        for (int off = 16; off; off >>= 1) {
            s += __shfl_down(s, off, 32);
            ss += __shfl_down(ss, off, 32);
        }
        if (w == 0) {
            const float mu = s / 524288.0f;
            const float var = ss / 524288.0f - mu * mu;
            smu = mu;
            srstd = rsqrtf(var + 1e-5f);
        }
    }
    __syncthreads();
    const float mu = smu, rstd = srstd;

    const long long base = (long long)b * 524288;
    const long long io = base + (long long)hr * 512 + w;
    const long long ig = base + (long long)(hr + 512) * 512 + w;

    const float xo = b2f(Xb[io]), xg = b2f(Xb[ig]);
    const float p1w = pw1_w[0], p1b = pw1_b[0];

    const float yo = ((xo - mu) * rstd * ln1_g[hr * 512 + w] + ln1_b[hr * 512 + w]) * p1w + p1b;
    const float yg = ((xg - mu) * rstd * ln1_g[(hr + 512) * 512 + w] + ln1_b[(hr + 512) * 512 + w]) * p1w + p1b;

    __shared__ float gb[514];
    gb[w + 1] = yo * sigm_fast(yg);
    if (w == 0) { gb[0] = 0.0f; gb[513] = 0.0f; }
    __syncthreads();

    const float z = gb[w] * dw1_w[0] + gb[w + 1] * dw1_w[1] + gb[w + 2] * dw1_w[2] + dw1_b[0];
    const float bnscale = rsqrtf(bn_v[0] + 1e-5f);

    const float u0 = z * dw2_w[0] + dw2_b[0];
    const float v0 = (u0 - bn_m[0]) * bnscale * bn_g[0] + bn_b[0];
    const float p0 = (v0 * sigm_fast(v0)) * pw2_w[0] + pw2_b[0];

    const float u1 = z * dw2_w[1] + dw2_b[1];
    const float v1 = (u1 - bn_m[0]) * bnscale * bn_g[0] + bn_b[0];
    const float p1 = (v1 * sigm_fast(v1)) * pw2_w[0] + pw2_b[0];

    Xb[io] = f2b(xo + p0);
    Xb[ig] = f2b(xg + p1);
}

// out = inputs + ((Xb - mu_b) * rstd_b * lnf_g + lnf_b). ROUND-22: per-block
// inline stats reduction (batch's 32 partials; blocks align to batches:
// 256 blocks/batch). 8 elems/thread. grid 8192 x 256.
__global__ void final_kernel(const float* __restrict__ inputs, const u16* __restrict__ Xb,
                             const float2* __restrict__ part,
                             const float* __restrict__ lnf_g, const float* __restrict__ lnf_b,
                             float* __restrict__ out)
{
    const int b = blockIdx.x >> 8;        // 256 blocks per batch
    const int tid = threadIdx.x;

    __shared__ float smu, srstd;
    if (tid < 32) {
        const float2 v = part[b * 32 + tid];
        float s = v.x, ss = v.y;
#pragma unroll
        for (int off = 16; off; off >>= 1) {
            s += __shfl_down(s, off, 32);
            ss += __shfl_down(ss, off, 32);
        }
        if (tid == 0) {
            const float mu = s / 524288.0f;
            const float var = ss / 524288.0f - mu * mu;
            smu = mu;
            srstd = rsqrtf(var + 1e-5f);
        }
    }
    __syncthreads();
    const float mu = smu, rstd = srstd;

    const long long i = ((long long)blockIdx.x * 256 + tid) * 8;
    const int r = (int)(i & 524287);
    const u16x8 xv = *(const u16x8*)(Xb + i);
    float o[8];
#pragma unroll
    for (int q = 0; q < 8; ++q) o[q] = (b2f(xv[q]) - mu) * rstd;
    const float4 g0 = *(const float4*)(lnf_g + r);
    const float4 g1 = *(const float4*)(lnf_g + r + 4);
    const float4 c0 = *(const float4*)(lnf_b + r);
    const float4 c1 = *(const float4*)(lnf_b + r + 4);
    const float4 n0 = *(const float4*)(inputs + i);
    const float4 n1 = *(const float4*)(inputs + i + 4);
    float4 w0, w1;
    w0.x = n0.x + o[0] * g0.x + c0.x; w0.y = n0.y + o[1] * g0.y + c0.y;
    w0.z = n0.z + o[2] * g0.z + c0.z; w0.w = n0.w + o[3] * g0.w + c0.w;
    w1.x = n1.x + o[4] * g1.x + c1.x; w1.y = n1.y + o[5] * g1.y + c1.y;
    w1.z = n1.z + o[6] * g1.z + c1.z; w1.w = n1.w + o[7] * g1.w + c1.w;
    *(float4*)(out + i) = w0;
    *(float4*)(out + i + 4) = w1;
}

extern "C" void kernel_launch(void* const* d_in, const int* in_sizes, int n_in,
                              void* d_out, int out_size, void* d_ws, size_t ws_size,
                              hipStream_t stream)
{
    (void)in_sizes; (void)n_in; (void)out_size; (void)ws_size;

    const float* inp   = (const float*)d_in[0];
    const float* l1_e1 = (const float*)d_in[1];
    const float* l1_d1 = (const float*)d_in[2];
    const float* l1_e2 = (const float*)d_in[3];
    const float* l1_d2 = (const float*)d_in[4];
    const float* wq    = (const float*)d_in[5];
    const float* bq    = (const float*)d_in[6];
    const float* wk    = (const float*)d_in[7];
    const float* bk    = (const float*)d_in[8];
    const float* wv    = (const float*)d_in[9];
    const float* bv    = (const float*)d_in[10];
    const float* wo    = (const float*)d_in[11];
    const float* bo    = (const float*)d_in[12];
    const float* ln1_g = (const float*)d_in[13];
    const float* ln1_b = (const float*)d_in[14];
    const float* pw1_w = (const float*)d_in[15];
    const float* pw1_b = (const float*)d_in[16];
    const float* dw1_w = (const float*)d_in[17];
    const float* dw1_b = (const float*)d_in[18];
    const float* dw2_w = (const float*)d_in[19];
    const float* dw2_b = (const float*)d_in[20];
    const float* bn_g  = (const float*)d_in[21];
    const float* bn_b  = (const float*)d_in[22];
    const float* bn_m  = (const float*)d_in[23];
    const float* bn_v  = (const float*)d_in[24];
    const float* pw2_w = (const float*)d_in[25];
    const float* pw2_b = (const float*)d_in[26];
    const float* l2_e1 = (const float*)d_in[27];
    const float* l2_d1 = (const float*)d_in[28];
    const float* l2_e2 = (const float*)d_in[29];
    const float* l2_d2 = (const float*)d_in[30];
    const float* lnf_g = (const float*)d_in[31];
    const float* lnf_b = (const float*)d_in[32];

    char* wsb = (char*)d_ws;
    u16*   Xb = (u16*)(wsb);                           // 33,554,432 B
    char*  U  = wsb + 33554432;                        // 67,108,864 B union region

    // precompute-phase overlays in U (batched-fold-friendly strides)
    u16* l1_d1t = (u16*)(U + 0);                       // 2 MB [1024][1024]
    u16* l2_d1t = (u16*)(U + 2097152);                 // 2 MB
    u16* l1_d2t = (u16*)(U + 4194304);                 // 1 MB [512][1024]
    u16* l2_d2t = (u16*)(U + 5242880);                 // 1 MB
    u16* l1_e1b = (u16*)(U + 6291456);                 // 1 MB [512][1024]
    u16* l2_e1b = (u16*)(U + 7340032);                 // 1 MB
    u16* l1_e2b = (u16*)(U + 8388608);                 // 2 MB [1024][1024]
    u16* l2_e2b = (u16*)(U + 10485760);                // 2 MB
    // LFFN-phase overlay
    u16* H = (u16*)U;                                  // [32768][1024] bf16 (64 MB)
    // MHLA-phase overlays
    u16*   QKV    = (u16*)U;                           // [32768][768] bf16 (48 MB)
    u16*   W2t_at = (u16*)(U + 50331648);              // [32][512][256] bf16 (8 MB)
    float* Bm     = (float*)(U + 58720256);            // [32][4][64][64] fp32 (2 MB)

    // persistent region
    char* P = wsb + 100663296;
    u16*    W1t_l1  = (u16*)(P + 0);                   // [1024][512]
    u16*    W1t_l2  = (u16*)(P + 1048576);
    u16*    W2t_l1  = (u16*)(P + 2097152);             // [512][1024]
    u16*    W2t_l2  = (u16*)(P + 3145728);
    u16*    qkvT    = (u16*)(P + 4194304);             // [768][512]
    float*  qkvBias = (float*)(P + 4980736);           // 768
    float2* part0   = (float2*)(P + 4983808);          // 1024 float2
    float2* part1   = (float2*)(P + 4992000);
    float*  BmPart  = (float*)(P + 8388608);           // [8][128][4096] fp32 (16 MB)

    auto G = [&](const u16* A, const u16* Bt, u16* oB,
                 const float* resF, const u16* resB, const float* bias, float2* parts,
                 int M, int N, int K, int lda, float alpha, int sw,
                 long long sA, long long sB, long long sC, int nb) {
        dim3 grid(N / 128, M / 128, nb);
        gemm_bf16<<<grid, 512, 0, stream>>>(A, Bt, oB, resF, resB, bias, parts,
                                            N, K, lda, alpha, sw, sA, sB, sC);
    };

    // ---- weight prep ----
    cvt_bf16_kernel<<<8192, 256, 0, stream>>>(inp, Xb);
    prep_tr<<<3072, dim3(32, 8), 0, stream>>>(l1_d1, l1_d2, l2_d1, l2_d2,
                                              l1_d1t, l1_d2t, l2_d1t, l2_d2t);
    prep_cvt<<<1536, 256, 0, stream>>>(l1_e1, l1_e2, l2_e1, l2_e2,
                                       l1_e1b, l1_e2b, l2_e1b, l2_e2b);
    qkvpack_kernel<<<1536, 256, 0, stream>>>(wq, wk, wv, qkvT);
    biaspack_kernel<<<3, 256, 0, stream>>>(bq, bk, bv, qkvBias);

    // ---- fold LFFN weight pairs (batched z=2): W1t = (e1@d1)^T, W2t = (e2@d2)^T
    G(l1_d1t, l1_e1b, W1t_l1, nullptr, nullptr, nullptr, nullptr,
      1024, 512, 1024, 1024, 1.0f, 0, 1048576LL, 524288LL, 524288LL, 2);
    G(l1_d2t, l1_e2b, W2t_l1, nullptr, nullptr, nullptr, nullptr,
      512, 1024, 1024, 1024, 1.0f, 0, 524288LL, 1048576LL, 524288LL, 2);

    // ---- LFFN1: Xb = inputs + 0.5 * (swish(x@W1) @ W2) ----
    G(Xb, W1t_l1, H, nullptr, nullptr, nullptr, nullptr, 32768, 1024, 512, 512, 1.0f, 1, 0, 0, 0, 1);
    G(H, W2t_l1, Xb, inp, nullptr, nullptr, nullptr, 32768, 512, 1024, 1024, 0.5f, 0, 0, 0, 0, 1);

    // ---- MHLA: Xb += Q_sm @ (Bm @ wo) + bo ----
    G(Xb, qkvT, QKV, nullptr, nullptr, qkvBias, nullptr, 32768, 768, 512, 512, 1.0f, 0, 0, 0, 0, 1);
    softmax_qkv<<<dim3(32, 16), 256, 0, stream>>>(QKV, 0.35355339059327373f);
    bm_kernel<<<dim3(128, 8), 256, 0, stream>>>(QKV, BmPart);
    bm_reduce<<<2048, 256, 0, stream>>>(BmPart, Bm);
    w2t_kernel<<<dim3(128, 8), 256, 0, stream>>>(Bm, wo, W2t_at);
    G(QKV, W2t_at, Xb, nullptr, Xb, bo, part0, 1024, 512, 256, 768, 1.0f, 0,
      786432LL, 131072LL, 524288LL, 32);

    // ---- Conv module: Xb += conv(Xb); stats inlined from part0 ----
    conv_kernel<<<16384, 512, 0, stream>>>(Xb, part0, ln1_g, ln1_b, pw1_w, pw1_b,
                                           dw1_w, dw1_b, dw2_w, dw2_b,
                                           bn_g, bn_b, bn_m, bn_v, pw2_w, pw2_b);

    // ---- LFFN2: Xb = Xb + 0.5 * (swish(x@W1) @ W2), fused stats ----
    G(Xb, W1t_l2, H, nullptr, nullptr, nullptr, nullptr, 32768, 1024, 512, 512, 1.0f, 1, 0, 0, 0, 1);
    G(H, W2t_l2, Xb, nullptr, Xb, nullptr, part1, 32768, 512, 1024, 1024, 0.5f, 0, 0, 0, 0, 1);

    // ---- Final LN + residual; stats inlined from part1 ----
    final_kernel<<<8192, 256, 0, stream>>>(inp, Xb, part1, lnf_g, lnf_b, (float*)d_out);
}